// Round 1
// baseline (1039.487 us; speedup 1.0000x reference)
//
#include <hip/hip_runtime.h>

// Problem dims
constexpr int Bb  = 64;      // batch
constexpr int Tt  = 1024;    // time
constexpr int Dd  = 288;     // padded input feature dim
constexpr int Ss  = 256;     // STATE_DIM
constexpr int ALa = 16;      // ACT_LEN
constexpr int Ll  = 256;     // LATENT
constexpr int Ee  = 512;     // ENC
constexpr int CC  = 8;       // scan chunk length
constexpr int NCh = 128;     // number of chunks (CC*NCh == Tt)
constexpr int NSC = 16;      // superchunks for boundary recurrence
constexpr int SC  = 8;       // chunk-boundaries per superchunk
constexpr int DEC_CHUNKS = 8;
constexpr int DEC_ROWS = (Bb*Tt)/DEC_CHUNKS;  // 8192 rows per chunk

#define LKY(v) ((v) >= 0.f ? (v) : 0.01f*(v))

using f32x4  = __attribute__((ext_vector_type(4))) float;
using short8 = __attribute__((ext_vector_type(8))) short;
typedef unsigned short ushort_t;

__device__ __forceinline__ unsigned short f2bf(float f){
  unsigned int u = __float_as_uint(f);
  u = (u + 0x7fffu + ((u >> 16) & 1u)) >> 16;   // RNE
  return (unsigned short)u;
}
__device__ __forceinline__ float bf2f(unsigned short h){
  return __uint_as_float(((unsigned int)h) << 16);
}

// ---------------------------------------------------------------------------
// Encoder dense layer, split-K: grid (row, N/32); 256 thr = 32 cols x 8 kslc.
// ---------------------------------------------------------------------------
__global__ __launch_bounds__(256) void enc_dense(
    const float* __restrict__ xin, int xstride,
    const float* __restrict__ W, const float* __restrict__ bias,
    float* __restrict__ out, int K, int N, int act)
{
  int b = blockIdx.x, col0 = blockIdx.y * 32;
  int tid = threadIdx.x;
  int tx = tid & 31, tk = tid >> 5;
  __shared__ float x[512];
  __shared__ float part[8][33];
  for (int k = tid; k < K; k += 256) x[k] = xin[(long)b*xstride + k];
  __syncthreads();
  int j = col0 + tx;
  float p0=0.f,p1=0.f,p2=0.f,p3=0.f;
  int iters = K >> 3;
  #pragma unroll 2
  for (int i = 0; i < iters; i += 4){
    int k0 = tk + 8*i;
    p0 = fmaf(x[k0     ], W[(long)(k0     )*N + j], p0);
    p1 = fmaf(x[k0 +  8], W[(long)(k0 +  8)*N + j], p1);
    p2 = fmaf(x[k0 + 16], W[(long)(k0 + 16)*N + j], p2);
    p3 = fmaf(x[k0 + 24], W[(long)(k0 + 24)*N + j], p3);
  }
  part[tk][tx] = (p0+p1)+(p2+p3);
  __syncthreads();
  if (tid < 32){
    float s = part[0][tid];
    #pragma unroll
    for (int q = 1; q < 8; ++q) s += part[q][tid];
    s += bias[col0 + tid];
    out[b*N + col0 + tid] = act ? LKY(s) : s;
  }
}

// ---------------------------------------------------------------------------
// 256x256 matmul C = X @ Y, split-K: block = row; 256 thr = 64 j4-groups x 4 kslc.
// Optional fp32 out + split planes ((k>>3)*256+n)*8+(k&7).
// ---------------------------------------------------------------------------
__global__ __launch_bounds__(256) void matmul_g(
    const float* __restrict__ X, const float* __restrict__ Y,
    float* __restrict__ Cf, ushort_t* __restrict__ Ch, ushort_t* __restrict__ Cl)
{
  int i = blockIdx.x;
  int tid = threadIdx.x;
  int jg = tid & 63, tk = tid >> 6;
  __shared__ float row[256];
  __shared__ float4 part[4][64];
  if (tid < 256) row[tid] = X[i*256 + tid];
  __syncthreads();
  int j4 = jg*4;
  float4 p0 = make_float4(0,0,0,0), p1 = make_float4(0,0,0,0);
  int kb = tk*64;
  #pragma unroll 4
  for (int k = kb; k < kb+64; k += 2){
    float x0 = row[k], x1 = row[k+1];
    float4 y0 = *(const float4*)&Y[(k  )*256 + j4];
    float4 y1 = *(const float4*)&Y[(k+1)*256 + j4];
    p0.x = fmaf(x0,y0.x,p0.x); p0.y = fmaf(x0,y0.y,p0.y);
    p0.z = fmaf(x0,y0.z,p0.z); p0.w = fmaf(x0,y0.w,p0.w);
    p1.x = fmaf(x1,y1.x,p1.x); p1.y = fmaf(x1,y1.y,p1.y);
    p1.z = fmaf(x1,y1.z,p1.z); p1.w = fmaf(x1,y1.w,p1.w);
  }
  p0.x+=p1.x; p0.y+=p1.y; p0.z+=p1.z; p0.w+=p1.w;
  part[tk][jg] = p0;
  __syncthreads();
  if (tid < 64){
    float4 s = part[0][tid];
    #pragma unroll
    for (int q = 1; q < 4; ++q){
      float4 v = part[q][tid];
      s.x+=v.x; s.y+=v.y; s.z+=v.z; s.w+=v.w;
    }
    int j = tid*4;
    if (Cf) *(float4*)&Cf[i*256 + j] = s;
    if (Ch){
      float vv[4] = {s.x,s.y,s.z,s.w};
      #pragma unroll
      for (int e = 0; e < 4; ++e){
        ushort_t h = f2bf(vv[e]);
        int o = ((i>>3)*256 + j + e)*8 + (i&7);
        Ch[o] = h; Cl[o] = f2bf(vv[e] - bf2f(h));
      }
    }
  }
}

// ---------------------------------------------------------------------------
// Split fp32 weight matrix (KxN) into hi/lo bf16 planes in fragment order.
// ---------------------------------------------------------------------------
__global__ __launch_bounds__(256) void prep_w(
    const float* __restrict__ W, ushort_t* __restrict__ Wh,
    ushort_t* __restrict__ Wl, int N)
{
  int o = blockIdx.x*256 + threadIdx.x;
  int j = o & 7;
  int rest = o >> 3;
  int n = rest % N;
  int t8 = rest / N;
  int k = t8*8 + j;
  float v = W[k*N + n];
  ushort_t h = f2bf(v);
  Wh[o] = h;
  Wl[o] = f2bf(v - bf2f(h));
}

// ---------------------------------------------------------------------------
// B_w^T plane for the scan's u-term: K padded 16->32 (zeros), N=256.
// ---------------------------------------------------------------------------
__global__ __launch_bounds__(256) void prep_bw(
    const float* __restrict__ B, ushort_t* __restrict__ Bh, ushort_t* __restrict__ Bl)
{
  int o = blockIdx.x*256 + threadIdx.x;     // 8192 total
  int j = o & 7, rest = o >> 3;
  int n = rest & 255, kq = rest >> 8;
  int k = kq*8 + j;
  float v = (k < ALa) ? B[k*256 + n] : 0.f;
  ushort_t h = f2bf(v);
  Bh[o] = h; Bl[o] = f2bf(v - bf2f(h));
}

// ---------------------------------------------------------------------------
// MFMA chunk scan (zero-init pass). Unchanged (known-good).
// ---------------------------------------------------------------------------
__device__ __forceinline__ void load_afrag(
    const ushort_t* __restrict__ P, int kq, int m0, short8* dst)
{
  #pragma unroll
  for (int mt = 0; mt < 4; ++mt)
    dst[mt] = *(const short8*)&P[((long)kq*256 + m0 + mt*16)*8];
}

__global__ __launch_bounds__(256) void scan_mfma(
    const float* __restrict__ in0,
    const ushort_t* __restrict__ AtH, const ushort_t* __restrict__ AtL,
    const ushort_t* __restrict__ BtH, const ushort_t* __restrict__ BtL,
    float* __restrict__ wend, float* __restrict__ zout)
{
  int chunk = blockIdx.x;
  int tid = threadIdx.x;
  int wave = tid >> 6, lane = tid & 63;
  int quad = lane >> 4, l16 = lane & 15;
  int mwave = wave * 64;
  int m0 = mwave + l16;

  __shared__ ushort_t StH[16384];
  __shared__ ushort_t StL[16384];

  short8 Bfh[4], Bfl[4];
  #pragma unroll
  for (int mt = 0; mt < 4; ++mt){
    int off = ((quad)*256 + m0 + mt*16)*8;
    Bfh[mt] = *(const short8*)&BtH[off];
    Bfl[mt] = *(const short8*)&BtL[off];
  }

  f32x4 acc[4][4];
  #pragma unroll
  for (int mt = 0; mt < 4; ++mt)
    #pragma unroll
    for (int nt = 0; nt < 4; ++nt) acc[mt][nt] = (f32x4){0.f,0.f,0.f,0.f};

  const float* ubase[4];
  #pragma unroll
  for (int nt = 0; nt < 4; ++nt)
    ubase[nt] = in0 + (long)(nt*16 + l16)*(Tt*Dd) + (Ss + ALa) + quad*8;

  short8 Ahb[2][4], Alb[2][4];

  for (int tt = 0; tt < CC; ++tt){
    int t = chunk*CC + tt;
    float4 uq[4][2];
    #pragma unroll
    for (int nt = 0; nt < 4; ++nt){
      if (quad < 2){
        const float* up = ubase[nt] + (long)t*Dd;
        uq[nt][0] = *(const float4*)up;
        uq[nt][1] = *(const float4*)(up + 4);
      } else {
        uq[nt][0] = make_float4(0,0,0,0); uq[nt][1] = make_float4(0,0,0,0);
      }
    }

    if (tt > 0){
      load_afrag(AtH, 0*4 + quad, m0, Ahb[0]);
      load_afrag(AtL, 0*4 + quad, m0, Alb[0]);
      #pragma unroll
      for (int kt = 0; kt < 8; ++kt){
        int cur = kt & 1;
        if (kt < 7){
          load_afrag(AtH, (kt+1)*4 + quad, m0, Ahb[cur^1]);
          load_afrag(AtL, (kt+1)*4 + quad, m0, Alb[cur^1]);
        }
        short8 Sbh[4], Sbl[4];
        #pragma unroll
        for (int nt = 0; nt < 4; ++nt){
          int off = ((kt*4 + quad)*64 + nt*16 + l16)*8;
          Sbh[nt] = *(const short8*)&StH[off];
          Sbl[nt] = *(const short8*)&StL[off];
        }
        #pragma unroll
        for (int mt = 0; mt < 4; ++mt)
          #pragma unroll
          for (int nt = 0; nt < 4; ++nt){
            acc[mt][nt] = __builtin_amdgcn_mfma_f32_16x16x32_bf16(Ahb[cur][mt], Sbh[nt], acc[mt][nt], 0,0,0);
            acc[mt][nt] = __builtin_amdgcn_mfma_f32_16x16x32_bf16(Ahb[cur][mt], Sbl[nt], acc[mt][nt], 0,0,0);
            acc[mt][nt] = __builtin_amdgcn_mfma_f32_16x16x32_bf16(Alb[cur][mt], Sbh[nt], acc[mt][nt], 0,0,0);
          }
      }
    }

    short8 uh[4], ul[4];
    #pragma unroll
    for (int nt = 0; nt < 4; ++nt){
      float v[8] = {uq[nt][0].x,uq[nt][0].y,uq[nt][0].z,uq[nt][0].w,
                    uq[nt][1].x,uq[nt][1].y,uq[nt][1].z,uq[nt][1].w};
      ushort_t hs[8], ls[8];
      #pragma unroll
      for (int j = 0; j < 8; ++j){
        hs[j] = f2bf(v[j]);
        ls[j] = f2bf(v[j] - bf2f(hs[j]));
      }
      uh[nt] = *(const short8*)hs; ul[nt] = *(const short8*)ls;
    }
    #pragma unroll
    for (int mt = 0; mt < 4; ++mt)
      #pragma unroll
      for (int nt = 0; nt < 4; ++nt){
        acc[mt][nt] = __builtin_amdgcn_mfma_f32_16x16x32_bf16(Bfh[mt], uh[nt], acc[mt][nt], 0,0,0);
        acc[mt][nt] = __builtin_amdgcn_mfma_f32_16x16x32_bf16(Bfh[mt], ul[nt], acc[mt][nt], 0,0,0);
        acc[mt][nt] = __builtin_amdgcn_mfma_f32_16x16x32_bf16(Bfl[mt], uh[nt], acc[mt][nt], 0,0,0);
      }

    __syncthreads();

    #pragma unroll
    for (int mt = 0; mt < 4; ++mt){
      int mb = mwave + mt*16 + quad*4;
      #pragma unroll
      for (int nt = 0; nt < 4; ++nt){
        int n = nt*16 + l16;
        f32x4 v = acc[mt][nt];
        *(float4*)&zout[((long)n*Tt + t)*Ll + mb] = make_float4(v[0],v[1],v[2],v[3]);
        if (tt == CC-1)
          *(float4*)&wend[((long)chunk*Bb + n)*Ll + mb] = make_float4(v[0],v[1],v[2],v[3]);
        #pragma unroll
        for (int reg = 0; reg < 4; ++reg){
          int m = mb + reg;
          ushort_t h = f2bf(v[reg]);
          ushort_t l = f2bf(v[reg] - bf2f(h));
          int so = ((m>>3)*64 + n)*8 + (m&7);
          StH[so] = h; StL[so] = l;
        }
        acc[mt][nt] = (f32x4){0.f,0.f,0.f,0.f};
      }
    }
    __syncthreads();
  }
}

// ---------------------------------------------------------------------------
// pass2 (MFMA): boundary recurrence done with split-bf16 MFMA.
// State stored transposed in LDS fragments: latent = M (256), batch = N (64),
// layout ((m>>3)*64 + n)*8 + (m&7) — identical to scan_mfma's state.
// A-operand fragments = matmul_g/prep_w plane order (A^T in fragment form).
// ---------------------------------------------------------------------------
__device__ __forceinline__ void frag_init_state(
    const float* __restrict__ src, ushort_t* StH, ushort_t* StL, int tid)
{
  // src layout: src[n*256 + m]  (n = batch 0..63, m = latent 0..255)
  #pragma unroll
  for (int it = 0; it < 8; ++it){
    int idx = tid + it*256;        // 0..2047
    int m8 = idx >> 6, n = idx & 63;
    const float* p = src + (long)n*256 + m8*8;
    float4 v0 = *(const float4*)p;
    float4 v1 = *(const float4*)(p + 4);
    float vv[8] = {v0.x,v0.y,v0.z,v0.w,v1.x,v1.y,v1.z,v1.w};
    ushort_t hs[8], ls[8];
    #pragma unroll
    for (int j = 0; j < 8; ++j){
      hs[j] = f2bf(vv[j]);
      ls[j] = f2bf(vv[j] - bf2f(hs[j]));
    }
    *(uint4*)&StH[(m8*64 + n)*8] = *(const uint4*)hs;
    *(uint4*)&StL[(m8*64 + n)*8] = *(const uint4*)ls;
  }
}

// One recurrence step: St <- P^T @ St + addin ; optionally write fp32 result.
// addin/out layout: [n*256 + m].
__device__ __forceinline__ void p2_step(
    const ushort_t* __restrict__ PH, const ushort_t* __restrict__ PL,
    const float* __restrict__ addin,
    ushort_t* StH, ushort_t* StL,
    float* __restrict__ out_f32,
    int wave, int lane)
{
  int quad = lane >> 4, l16 = lane & 15;
  int mwave = wave*64, m0 = mwave + l16;

  f32x4 acc[4][4];
  #pragma unroll
  for (int mt = 0; mt < 4; ++mt){
    int mb = mwave + mt*16 + quad*4;
    #pragma unroll
    for (int nt = 0; nt < 4; ++nt){
      int n = nt*16 + l16;
      float4 v = *(const float4*)&addin[(long)n*256 + mb];
      acc[mt][nt] = (f32x4){v.x, v.y, v.z, v.w};
    }
  }

  short8 Ahb[2][4], Alb[2][4];
  load_afrag(PH, 0*4 + quad, m0, Ahb[0]);
  load_afrag(PL, 0*4 + quad, m0, Alb[0]);
  #pragma unroll
  for (int kt = 0; kt < 8; ++kt){
    int cur = kt & 1;
    if (kt < 7){
      load_afrag(PH, (kt+1)*4 + quad, m0, Ahb[cur^1]);
      load_afrag(PL, (kt+1)*4 + quad, m0, Alb[cur^1]);
    }
    short8 Sbh[4], Sbl[4];
    #pragma unroll
    for (int nt = 0; nt < 4; ++nt){
      int off = ((kt*4 + quad)*64 + nt*16 + l16)*8;
      Sbh[nt] = *(const short8*)&StH[off];
      Sbl[nt] = *(const short8*)&StL[off];
    }
    #pragma unroll
    for (int mt = 0; mt < 4; ++mt)
      #pragma unroll
      for (int nt = 0; nt < 4; ++nt){
        acc[mt][nt] = __builtin_amdgcn_mfma_f32_16x16x32_bf16(Ahb[cur][mt], Sbh[nt], acc[mt][nt], 0,0,0);
        acc[mt][nt] = __builtin_amdgcn_mfma_f32_16x16x32_bf16(Ahb[cur][mt], Sbl[nt], acc[mt][nt], 0,0,0);
        acc[mt][nt] = __builtin_amdgcn_mfma_f32_16x16x32_bf16(Alb[cur][mt], Sbh[nt], acc[mt][nt], 0,0,0);
      }
  }

  __syncthreads();   // all waves done reading St

  #pragma unroll
  for (int mt = 0; mt < 4; ++mt){
    int mb = mwave + mt*16 + quad*4;
    #pragma unroll
    for (int nt = 0; nt < 4; ++nt){
      int n = nt*16 + l16;
      f32x4 v = acc[mt][nt];
      if (out_f32)
        *(float4*)&out_f32[(long)n*256 + mb] = make_float4(v[0],v[1],v[2],v[3]);
      #pragma unroll
      for (int reg = 0; reg < 4; ++reg){
        int m = mb + reg;
        ushort_t h = f2bf(v[reg]);
        int so = ((m>>3)*64 + n)*8 + (m&7);
        StH[so] = h;
        StL[so] = f2bf(v[reg] - bf2f(h));
      }
    }
  }
  __syncthreads();
}

// lend[s] = zero-init combine of wend[8s..8s+7] over A^8.  16 blocks.
__global__ __launch_bounds__(256) void pass2_local_mfma(
    const ushort_t* __restrict__ A8H, const ushort_t* __restrict__ A8L,
    const float* __restrict__ wend, float* __restrict__ lend)
{
  int s = blockIdx.x;
  int tid = threadIdx.x;
  int wave = tid >> 6, lane = tid & 63;
  __shared__ ushort_t StH[16384], StL[16384];
  frag_init_state(wend + (long)(s*SC)*Bb*256, StH, StL, tid);
  __syncthreads();
  for (int i = 1; i < SC; ++i)
    p2_step(A8H, A8L, wend + (long)(s*SC + i)*Bb*256, StH, StL,
            (i == SC-1) ? (lend + (long)s*Bb*256) : nullptr, wave, lane);
}

// Superchunk-level serial chain over A^64; writes inits at chunks (s+1)*8.
__global__ __launch_bounds__(256) void pass2_global_mfma(
    const ushort_t* __restrict__ A64H, const ushort_t* __restrict__ A64L,
    const float* __restrict__ lend, float* __restrict__ inits)
{
  int tid = threadIdx.x;
  int wave = tid >> 6, lane = tid & 63;
  __shared__ ushort_t StH[16384], StL[16384];
  frag_init_state(inits, StH, StL, tid);   // chunk 0 = z0
  __syncthreads();
  for (int s = 0; s < NSC-1; ++s)
    p2_step(A64H, A64L, lend + (long)s*Bb*256, StH, StL,
            inits + (long)((s+1)*SC)*Bb*256, wave, lane);
}

// Replay within each superchunk: fills inits at chunks 8s+1..8s+7.  16 blocks.
__global__ __launch_bounds__(256) void pass2_replay_mfma(
    const ushort_t* __restrict__ A8H, const ushort_t* __restrict__ A8L,
    const float* __restrict__ wend, float* __restrict__ inits)
{
  int s = blockIdx.x;
  int tid = threadIdx.x;
  int wave = tid >> 6, lane = tid & 63;
  __shared__ ushort_t StH[16384], StL[16384];
  frag_init_state(inits + (long)(s*SC)*Bb*256, StH, StL, tid);
  __syncthreads();
  for (int i = 0; i < SC-1; ++i)
    p2_step(A8H, A8L, wend + (long)(s*SC + i)*Bb*256, StH, StL,
            inits + (long)(s*SC + i + 1)*Bb*256, wave, lane);
}

// ---------------------------------------------------------------------------
// Correction GEMMs: out[b, c*CC+j, :] += inits[c*64+b] @ A^(j+1). Unchanged.
// ---------------------------------------------------------------------------
__global__ __launch_bounds__(256) void gemm_corr(
    const float* __restrict__ inits, const ushort_t* __restrict__ AjH,
    const ushort_t* __restrict__ AjL, float* __restrict__ out)
{
  int jz = blockIdx.z;
  const ushort_t* Whp = AjH + (long)jz*65536;
  const ushort_t* Wlp = AjL + (long)jz*65536;
  __shared__ __align__(16) ushort_t Xh[4*128*8], Xl[4*128*8];
  __shared__ __align__(16) ushort_t Wh[4*128*8], Wl[4*128*8];

  int tid  = threadIdx.x;
  int wave = tid >> 6, lane = tid & 63;
  int wm = wave & 1, wn = wave >> 1;
  int quad = lane >> 4, l16 = lane & 15;
  int row0 = blockIdx.y * 128;
  int col0 = blockIdx.x * 128;

  f32x4 acc[4][4];
  #pragma unroll
  for (int mt = 0; mt < 4; ++mt)
    #pragma unroll
    for (int nt = 0; nt < 4; ++nt) acc[mt][nt] = (f32x4){0.f,0.f,0.f,0.f};

  for (int kt = 0; kt < 8; ++kt){
    #pragma unroll
    for (int it = 0; it < 2; ++it){
      int idx = tid + it*256;
      int q = idx >> 7, m = idx & 127;
      const float* xp = &inits[(long)(row0 + m)*256 + kt*32 + q*8];
      float4 v0 = *(const float4*)xp;
      float4 v1 = *(const float4*)(xp + 4);
      float vv[8] = {v0.x,v0.y,v0.z,v0.w,v1.x,v1.y,v1.z,v1.w};
      ushort_t hs[8], ls[8];
      #pragma unroll
      for (int j = 0; j < 8; ++j){
        hs[j] = f2bf(vv[j]);
        ls[j] = f2bf(vv[j] - bf2f(hs[j]));
      }
      *(uint4*)&Xh[(q*128 + m)*8] = *(const uint4*)hs;
      *(uint4*)&Xl[(q*128 + m)*8] = *(const uint4*)ls;
      int n = idx & 127;
      long src = (long)(kt*4 + q)*256 + col0 + n;
      ((uint4*)Wh)[q*128 + n] = ((const uint4*)Whp)[src];
      ((uint4*)Wl)[q*128 + n] = ((const uint4*)Wlp)[src];
    }
    __syncthreads();
    short8 ah[4], al[4], bh[4], bl[4];
    #pragma unroll
    for (int mt = 0; mt < 4; ++mt){
      int off = (quad*128 + wm*64 + mt*16 + l16)*8;
      ah[mt] = *(const short8*)&Xh[off];
      al[mt] = *(const short8*)&Xl[off];
    }
    #pragma unroll
    for (int nt = 0; nt < 4; ++nt){
      int off = (quad*128 + wn*64 + nt*16 + l16)*8;
      bh[nt] = *(const short8*)&Wh[off];
      bl[nt] = *(const short8*)&Wl[off];
    }
    #pragma unroll
    for (int mt = 0; mt < 4; ++mt)
      #pragma unroll
      for (int nt = 0; nt < 4; ++nt){
        acc[mt][nt] = __builtin_amdgcn_mfma_f32_16x16x32_bf16(ah[mt], bh[nt], acc[mt][nt], 0,0,0);
        acc[mt][nt] = __builtin_amdgcn_mfma_f32_16x16x32_bf16(ah[mt], bl[nt], acc[mt][nt], 0,0,0);
        acc[mt][nt] = __builtin_amdgcn_mfma_f32_16x16x32_bf16(al[mt], bh[nt], acc[mt][nt], 0,0,0);
      }
    __syncthreads();
  }

  #pragma unroll
  for (int mt = 0; mt < 4; ++mt){
    #pragma unroll
    for (int nt = 0; nt < 4; ++nt){
      int col = col0 + wn*64 + nt*16 + l16;
      #pragma unroll
      for (int reg = 0; reg < 4; ++reg){
        int row = row0 + wm*64 + mt*16 + quad*4 + reg;
        int b = row & 63, c = row >> 6;
        int t = c*CC + jz;
        long addr = ((long)b*Tt + t)*Ll + col;
        out[addr] += acc[mt][nt][reg];
      }
    }
  }
}

// ---------------------------------------------------------------------------
// Decoder split-bf16 MFMA GEMM (unchanged; launched at 64x128).
// ---------------------------------------------------------------------------
template<int BM, int BN, bool INS, bool OUTS>
__global__ __launch_bounds__(256) void gemm_mfma(
    const float* __restrict__ X,
    const ushort_t* __restrict__ Xhp, const ushort_t* __restrict__ Xlp,
    const ushort_t* __restrict__ Whp, const ushort_t* __restrict__ Wlp,
    const float* __restrict__ bias, float* __restrict__ Y,
    ushort_t* __restrict__ Yh, ushort_t* __restrict__ Yl,
    int Mrows, int K, int N, int act)
{
  constexpr int BMh = BM/2, BNh = BN/2;
  constexpr int MT = BM/32, NT = BN/32;
  __shared__ __align__(16) ushort_t Xh[4*BM*8], Xl[4*BM*8];
  __shared__ __align__(16) ushort_t Wh[4*BN*8], Wl[4*BN*8];

  int tid  = threadIdx.x;
  int wave = tid >> 6, lane = tid & 63;
  int wm = wave & 1, wn = wave >> 1;
  int quad = lane >> 4, l16 = lane & 15;
  long row0 = (long)blockIdx.y * BM;
  int col0 = blockIdx.x * BN;

  f32x4 acc[MT][NT];
  #pragma unroll
  for (int mt = 0; mt < MT; ++mt)
    #pragma unroll
    for (int nt = 0; nt < NT; ++nt) acc[mt][nt] = (f32x4){0.f,0.f,0.f,0.f};

  for (int kt = 0; kt < K; kt += 32){
    int ktile = kt >> 5;
    if constexpr (INS){
      #pragma unroll
      for (int it = 0; it < (BM*4)/256; ++it){
        int idx = tid + it*256;
        int q = idx / BM, m = idx % BM;
        long src = (long)(ktile*4 + q)*Mrows + row0 + m;
        ((uint4*)Xh)[q*BM + m] = ((const uint4*)Xhp)[src];
        ((uint4*)Xl)[q*BM + m] = ((const uint4*)Xlp)[src];
      }
    } else {
      #pragma unroll
      for (int it = 0; it < (BM*4)/256; ++it){
        int idx = tid + it*256;
        int q = idx / BM, m = idx % BM;
        const float* xp = &X[(row0 + m)*(long)K + kt + q*8];
        float4 v0 = *(const float4*)xp;
        float4 v1 = *(const float4*)(xp + 4);
        float vv[8] = {v0.x,v0.y,v0.z,v0.w,v1.x,v1.y,v1.z,v1.w};
        ushort_t hs[8], ls[8];
        #pragma unroll
        for (int j = 0; j < 8; ++j){
          hs[j] = f2bf(vv[j]);
          ls[j] = f2bf(vv[j] - bf2f(hs[j]));
        }
        *(uint4*)&Xh[(q*BM + m)*8] = *(const uint4*)hs;
        *(uint4*)&Xl[(q*BM + m)*8] = *(const uint4*)ls;
      }
    }
    #pragma unroll
    for (int it = 0; it < (BN*4)/256; ++it){
      int idx = tid + it*256;
      int q = idx / BN, n = idx % BN;
      long src = (long)(ktile*4 + q)*N + col0 + n;
      ((uint4*)Wh)[q*BN + n] = ((const uint4*)Whp)[src];
      ((uint4*)Wl)[q*BN + n] = ((const uint4*)Wlp)[src];
    }
    __syncthreads();

    short8 ah[MT], al[MT], bh[NT], bl[NT];
    #pragma unroll
    for (int mt = 0; mt < MT; ++mt){
      int off = (quad*BM + wm*BMh + mt*16 + l16)*8;
      ah[mt] = *(const short8*)&Xh[off];
      al[mt] = *(const short8*)&Xl[off];
    }
    #pragma unroll
    for (int nt = 0; nt < NT; ++nt){
      int off = (quad*BN + wn*BNh + nt*16 + l16)*8;
      bh[nt] = *(const short8*)&Wh[off];
      bl[nt] = *(const short8*)&Wl[off];
    }
    #pragma unroll
    for (int mt = 0; mt < MT; ++mt)
      #pragma unroll
      for (int nt = 0; nt < NT; ++nt){
        acc[mt][nt] = __builtin_amdgcn_mfma_f32_16x16x32_bf16(ah[mt], bh[nt], acc[mt][nt], 0, 0, 0);
        acc[mt][nt] = __builtin_amdgcn_mfma_f32_16x16x32_bf16(ah[mt], bl[nt], acc[mt][nt], 0, 0, 0);
        acc[mt][nt] = __builtin_amdgcn_mfma_f32_16x16x32_bf16(al[mt], bh[nt], acc[mt][nt], 0, 0, 0);
      }
    __syncthreads();
  }

  #pragma unroll
  for (int mt = 0; mt < MT; ++mt){
    long rowb = row0 + wm*BMh + mt*16 + quad*4;
    #pragma unroll
    for (int nt = 0; nt < NT; ++nt){
      int col = col0 + wn*BNh + nt*16 + l16;
      float bs = bias[col];
      #pragma unroll
      for (int reg = 0; reg < 4; ++reg){
        float y = acc[mt][nt][reg] + bs;
        if (act) y = LKY(y);
        long row = rowb + reg;
        if constexpr (OUTS){
          ushort_t h = f2bf(y);
          ushort_t l = f2bf(y - bf2f(h));
          long off = ((long)(col >> 3)*Mrows + row)*8 + (col & 7);
          Yh[off] = h; Yl[off] = l;
        } else {
          Y[row*(long)N + col] = y;
        }
      }
    }
  }
}

// ---------------------------------------------------------------------------
extern "C" void kernel_launch(void* const* d_in, const int* in_sizes, int n_in,
                              void* d_out, int out_size, void* d_ws, size_t ws_size,
                              hipStream_t stream) {
  const float* in0    = (const float*)d_in[0];
  const float* enc_w1 = (const float*)d_in[1];
  const float* enc_b1 = (const float*)d_in[2];
  const float* enc_w2 = (const float*)d_in[3];
  const float* enc_b2 = (const float*)d_in[4];
  const float* enc_w3 = (const float*)d_in[5];
  const float* enc_b3 = (const float*)d_in[6];
  const float* A_w    = (const float*)d_in[7];
  const float* B_w    = (const float*)d_in[8];
  const float* dec_w1 = (const float*)d_in[9];
  const float* dec_b1 = (const float*)d_in[10];
  const float* dec_w2 = (const float*)d_in[11];
  const float* dec_b2 = (const float*)d_in[12];
  const float* dec_w3 = (const float*)d_in[13];
  const float* dec_b3 = (const float*)d_in[14];
  float* out = (float*)d_out;

  // ---- workspace layout (float slots); total 9,437,184 fl = 37.75 MB ----
  float* ws    = (float*)d_ws;
  float* h1enc = ws;                      // 32768
  float* h2enc = ws + 32768;              // 32768
  float* s2    = ws + 65536;              // A^2
  float* s3    = ws + 131072;             // A^3
  float* s4    = ws + 196608;             // A^4
  float* s8    = ws + 262144;             // A^8
  float* s16   = ws + 327680;
  float* s32   = ws + 393216;
  float* s64   = ws + 458752;             // A^64
  ushort_t* Whp_d = (ushort_t*)(ws + 524288);   // decoder W planes
  ushort_t* Wlp_d = (ushort_t*)(ws + 786432);
  float* Rf    = ws + 1048576;            // R-pool: 8,388,608 fl
  // scan-phase layout of R:
  ushort_t* AjH = (ushort_t*)Rf;                // 8 planes x 65536 ush
  ushort_t* AjL = (ushort_t*)(Rf + 262144);
  ushort_t* BtH = (ushort_t*)(Rf + 524288);     // 8192 ush
  ushort_t* BtL = BtH + 8192;
  float* wend  = Rf + 532480;             // 2,097,152
  float* inits = Rf + 2629632;            // 2,097,152 (inits[0] = z0)
  float* lend  = Rf + 4726784;            // 262,144 (ends at 4,988,928)
  ushort_t* A64H = (ushort_t*)(Rf + 4988928);   // 65536 ush (32768 fl)
  ushort_t* A64L = (ushort_t*)(Rf + 5021696);   // 65536 ush
  // decoder-phase aliases of R (scan data dead by then):
  ushort_t* h1h = (ushort_t*)Rf;
  ushort_t* h1l = (ushort_t*)(Rf + 2097152);
  ushort_t* h2h = (ushort_t*)(Rf + 4194304);
  ushort_t* h2l = (ushort_t*)(Rf + 6291456);
  // A^8 hi/lo planes in fragment order already exist: AjH/AjL plane 7.
  ushort_t* A8H = AjH + 7*65536;
  ushort_t* A8L = AjL + 7*65536;

  // Encoder (only t=0 feeds the scan) -> z0 into inits[0]
  enc_dense<<<dim3(64,16), 256, 0, stream>>>(in0, Tt*Dd, enc_w1, enc_b1, h1enc, 256, 512, 1);
  enc_dense<<<dim3(64,16), 256, 0, stream>>>(h1enc, 512, enc_w2, enc_b2, h2enc, 512, 512, 1);
  enc_dense<<<dim3(64, 8), 256, 0, stream>>>(h2enc, 512, enc_w3, enc_b3, inits, 512, 256, 1);

  // A^j planes (j=1..8) + A^64 planes for pass2
  prep_w<<<256, 256, 0, stream>>>(A_w, AjH, AjL, 256);                       // A^1 plane
  prep_bw<<<32, 256, 0, stream>>>(B_w, BtH, BtL);
  matmul_g<<<256, 256, 0, stream>>>(A_w, A_w, s2, AjH+1*65536, AjL+1*65536); // A^2
  matmul_g<<<256, 256, 0, stream>>>(s2, A_w, s3, AjH+2*65536, AjL+2*65536);  // A^3
  matmul_g<<<256, 256, 0, stream>>>(s2, s2, s4, AjH+3*65536, AjL+3*65536);   // A^4
  matmul_g<<<256, 256, 0, stream>>>(s4, A_w, nullptr, AjH+4*65536, AjL+4*65536); // A^5
  matmul_g<<<256, 256, 0, stream>>>(s4, s2, nullptr, AjH+5*65536, AjL+5*65536);  // A^6
  matmul_g<<<256, 256, 0, stream>>>(s4, s3, nullptr, AjH+6*65536, AjL+6*65536);  // A^7
  matmul_g<<<256, 256, 0, stream>>>(s4, s4, s8, A8H, A8L);                   // A^8 (+planes)
  matmul_g<<<256, 256, 0, stream>>>(s8, s8, s16, nullptr, nullptr);          // A^16
  matmul_g<<<256, 256, 0, stream>>>(s16, s16, s32, nullptr, nullptr);        // A^32
  matmul_g<<<256, 256, 0, stream>>>(s32, s32, s64, A64H, A64L);              // A^64 (+planes)

  // Decoder weight planes
  prep_w<<<512,  256, 0, stream>>>(dec_w1, Whp_d,          Wlp_d,          512);
  prep_w<<<1024, 256, 0, stream>>>(dec_w2, Whp_d + 131072, Wlp_d + 131072, 512);
  prep_w<<<512,  256, 0, stream>>>(dec_w3, Whp_d + 393216, Wlp_d + 393216, 256);

  // Pass 1: MFMA zero-init chunk scans; w[t] -> d_out, ends -> wend
  scan_mfma<<<NCh, 256, 0, stream>>>(in0, AjH, AjL, BtH, BtL, wend, out);
  // Pass 2: hierarchical boundary recurrence, now split-bf16 MFMA
  pass2_local_mfma <<<NSC, 256, 0, stream>>>(A8H, A8L, wend, lend);
  pass2_global_mfma<<<1,   256, 0, stream>>>(A64H, A64L, lend, inits);
  pass2_replay_mfma<<<NSC, 256, 0, stream>>>(A8H, A8L, wend, inits);
  // Pass 3 (parallel corrections): out[b, c*8+j, :] += inits[c] @ A^(j+1)
  gemm_corr<<<dim3(2, 64, 8), 256, 0, stream>>>(inits, AjH, AjL, out);

  // Decoder: 3-layer MLP, split-bf16 MFMA, 64x128 tiles
  for (int rc = 0; rc < DEC_CHUNKS; ++rc){
    const float* zc = out + (long)rc*DEC_ROWS*Ll;
    float* oc       = out + (long)rc*DEC_ROWS*Ll;
    gemm_mfma<64,128,false,true><<<dim3(Ee/128, DEC_ROWS/64), 256, 0, stream>>>(
        zc, nullptr, nullptr, Whp_d, Wlp_d, dec_b1, nullptr, h1h, h1l, DEC_ROWS, Ll, Ee, 1);
    gemm_mfma<64,128,true,true><<<dim3(Ee/128, DEC_ROWS/64), 256, 0, stream>>>(
        nullptr, h1h, h1l, Whp_d + 131072, Wlp_d + 131072, dec_b2, nullptr, h2h, h2l, DEC_ROWS, Ee, Ee, 1);
    gemm_mfma<64,128,true,false><<<dim3(Ss/128, DEC_ROWS/64), 256, 0, stream>>>(
        nullptr, h2h, h2l, Whp_d + 393216, Wlp_d + 393216, dec_b3, oc, nullptr, nullptr, DEC_ROWS, Ee, Ss, 0);
  }
}

// Round 2
// 1006.672 us; speedup vs baseline: 1.0326x; 1.0326x over previous
//
#include <hip/hip_runtime.h>

// Problem dims
constexpr int Bb  = 64;      // batch
constexpr int Tt  = 1024;    // time
constexpr int Dd  = 288;     // padded input feature dim
constexpr int Ss  = 256;     // STATE_DIM
constexpr int ALa = 16;      // ACT_LEN
constexpr int Ll  = 256;     // LATENT
constexpr int Ee  = 512;     // ENC
constexpr int CC  = 8;       // scan chunk length
constexpr int NCh = 128;     // number of chunks (CC*NCh == Tt)
constexpr int NSC = 16;      // superchunks for boundary recurrence
constexpr int SC  = 8;       // chunk-boundaries per superchunk
constexpr int DEC_CHUNKS = 8;
constexpr int DEC_ROWS = (Bb*Tt)/DEC_CHUNKS;  // 8192 rows per chunk

#define LKY(v) ((v) >= 0.f ? (v) : 0.01f*(v))

using f32x4  = __attribute__((ext_vector_type(4))) float;
using short8 = __attribute__((ext_vector_type(8))) short;
typedef unsigned short ushort_t;

__device__ __forceinline__ unsigned short f2bf(float f){
  unsigned int u = __float_as_uint(f);
  u = (u + 0x7fffu + ((u >> 16) & 1u)) >> 16;   // RNE
  return (unsigned short)u;
}
__device__ __forceinline__ float bf2f(unsigned short h){
  return __uint_as_float(((unsigned int)h) << 16);
}

// ---------------------------------------------------------------------------
// Encoder dense layer, split-K: grid (row, N/32); 256 thr = 32 cols x 8 kslc.
// ---------------------------------------------------------------------------
__global__ __launch_bounds__(256) void enc_dense(
    const float* __restrict__ xin, int xstride,
    const float* __restrict__ W, const float* __restrict__ bias,
    float* __restrict__ out, int K, int N, int act)
{
  int b = blockIdx.x, col0 = blockIdx.y * 32;
  int tid = threadIdx.x;
  int tx = tid & 31, tk = tid >> 5;
  __shared__ float x[512];
  __shared__ float part[8][33];
  for (int k = tid; k < K; k += 256) x[k] = xin[(long)b*xstride + k];
  __syncthreads();
  int j = col0 + tx;
  float p0=0.f,p1=0.f,p2=0.f,p3=0.f;
  int iters = K >> 3;
  #pragma unroll 2
  for (int i = 0; i < iters; i += 4){
    int k0 = tk + 8*i;
    p0 = fmaf(x[k0     ], W[(long)(k0     )*N + j], p0);
    p1 = fmaf(x[k0 +  8], W[(long)(k0 +  8)*N + j], p1);
    p2 = fmaf(x[k0 + 16], W[(long)(k0 + 16)*N + j], p2);
    p3 = fmaf(x[k0 + 24], W[(long)(k0 + 24)*N + j], p3);
  }
  part[tk][tx] = (p0+p1)+(p2+p3);
  __syncthreads();
  if (tid < 32){
    float s = part[0][tid];
    #pragma unroll
    for (int q = 1; q < 8; ++q) s += part[q][tid];
    s += bias[col0 + tid];
    out[b*N + col0 + tid] = act ? LKY(s) : s;
  }
}

// ---------------------------------------------------------------------------
// 256x256 matmul C = X @ Y, split-K: block = row; 256 thr = 64 j4-groups x 4 kslc.
// Optional fp32 out + split planes ((k>>3)*256+n)*8+(k&7).
// ---------------------------------------------------------------------------
__global__ __launch_bounds__(256) void matmul_g(
    const float* __restrict__ X, const float* __restrict__ Y,
    float* __restrict__ Cf, ushort_t* __restrict__ Ch, ushort_t* __restrict__ Cl)
{
  int i = blockIdx.x;
  int tid = threadIdx.x;
  int jg = tid & 63, tk = tid >> 6;
  __shared__ float row[256];
  __shared__ float4 part[4][64];
  if (tid < 256) row[tid] = X[i*256 + tid];
  __syncthreads();
  int j4 = jg*4;
  float4 p0 = make_float4(0,0,0,0), p1 = make_float4(0,0,0,0);
  int kb = tk*64;
  #pragma unroll 4
  for (int k = kb; k < kb+64; k += 2){
    float x0 = row[k], x1 = row[k+1];
    float4 y0 = *(const float4*)&Y[(k  )*256 + j4];
    float4 y1 = *(const float4*)&Y[(k+1)*256 + j4];
    p0.x = fmaf(x0,y0.x,p0.x); p0.y = fmaf(x0,y0.y,p0.y);
    p0.z = fmaf(x0,y0.z,p0.z); p0.w = fmaf(x0,y0.w,p0.w);
    p1.x = fmaf(x1,y1.x,p1.x); p1.y = fmaf(x1,y1.y,p1.y);
    p1.z = fmaf(x1,y1.z,p1.z); p1.w = fmaf(x1,y1.w,p1.w);
  }
  p0.x+=p1.x; p0.y+=p1.y; p0.z+=p1.z; p0.w+=p1.w;
  part[tk][jg] = p0;
  __syncthreads();
  if (tid < 64){
    float4 s = part[0][tid];
    #pragma unroll
    for (int q = 1; q < 4; ++q){
      float4 v = part[q][tid];
      s.x+=v.x; s.y+=v.y; s.z+=v.z; s.w+=v.w;
    }
    int j = tid*4;
    if (Cf) *(float4*)&Cf[i*256 + j] = s;
    if (Ch){
      float vv[4] = {s.x,s.y,s.z,s.w};
      #pragma unroll
      for (int e = 0; e < 4; ++e){
        ushort_t h = f2bf(vv[e]);
        int o = ((i>>3)*256 + j + e)*8 + (i&7);
        Ch[o] = h; Cl[o] = f2bf(vv[e] - bf2f(h));
      }
    }
  }
}

// ---------------------------------------------------------------------------
// Split fp32 weight matrix (KxN) into hi/lo bf16 planes in fragment order.
// ---------------------------------------------------------------------------
__global__ __launch_bounds__(256) void prep_w(
    const float* __restrict__ W, ushort_t* __restrict__ Wh,
    ushort_t* __restrict__ Wl, int N)
{
  int o = blockIdx.x*256 + threadIdx.x;
  int j = o & 7;
  int rest = o >> 3;
  int n = rest % N;
  int t8 = rest / N;
  int k = t8*8 + j;
  float v = W[k*N + n];
  ushort_t h = f2bf(v);
  Wh[o] = h;
  Wl[o] = f2bf(v - bf2f(h));
}

// ---------------------------------------------------------------------------
// B_w^T plane for the scan's u-term: K padded 16->32 (zeros), N=256.
// ---------------------------------------------------------------------------
__global__ __launch_bounds__(256) void prep_bw(
    const float* __restrict__ B, ushort_t* __restrict__ Bh, ushort_t* __restrict__ Bl)
{
  int o = blockIdx.x*256 + threadIdx.x;     // 8192 total
  int j = o & 7, rest = o >> 3;
  int n = rest & 255, kq = rest >> 8;
  int k = kq*8 + j;
  float v = (k < ALa) ? B[k*256 + n] : 0.f;
  ushort_t h = f2bf(v);
  Bh[o] = h; Bl[o] = f2bf(v - bf2f(h));
}

// ---------------------------------------------------------------------------
// MFMA chunk scan (zero-init pass). Unchanged (known-good).
// ---------------------------------------------------------------------------
__device__ __forceinline__ void load_afrag(
    const ushort_t* __restrict__ P, int kq, int m0, short8* dst)
{
  #pragma unroll
  for (int mt = 0; mt < 4; ++mt)
    dst[mt] = *(const short8*)&P[((long)kq*256 + m0 + mt*16)*8];
}

__global__ __launch_bounds__(256) void scan_mfma(
    const float* __restrict__ in0,
    const ushort_t* __restrict__ AtH, const ushort_t* __restrict__ AtL,
    const ushort_t* __restrict__ BtH, const ushort_t* __restrict__ BtL,
    float* __restrict__ wend, float* __restrict__ zout)
{
  int chunk = blockIdx.x;
  int tid = threadIdx.x;
  int wave = tid >> 6, lane = tid & 63;
  int quad = lane >> 4, l16 = lane & 15;
  int mwave = wave * 64;
  int m0 = mwave + l16;

  __shared__ ushort_t StH[16384];
  __shared__ ushort_t StL[16384];

  short8 Bfh[4], Bfl[4];
  #pragma unroll
  for (int mt = 0; mt < 4; ++mt){
    int off = ((quad)*256 + m0 + mt*16)*8;
    Bfh[mt] = *(const short8*)&BtH[off];
    Bfl[mt] = *(const short8*)&BtL[off];
  }

  f32x4 acc[4][4];
  #pragma unroll
  for (int mt = 0; mt < 4; ++mt)
    #pragma unroll
    for (int nt = 0; nt < 4; ++nt) acc[mt][nt] = (f32x4){0.f,0.f,0.f,0.f};

  const float* ubase[4];
  #pragma unroll
  for (int nt = 0; nt < 4; ++nt)
    ubase[nt] = in0 + (long)(nt*16 + l16)*(Tt*Dd) + (Ss + ALa) + quad*8;

  short8 Ahb[2][4], Alb[2][4];

  for (int tt = 0; tt < CC; ++tt){
    int t = chunk*CC + tt;
    float4 uq[4][2];
    #pragma unroll
    for (int nt = 0; nt < 4; ++nt){
      if (quad < 2){
        const float* up = ubase[nt] + (long)t*Dd;
        uq[nt][0] = *(const float4*)up;
        uq[nt][1] = *(const float4*)(up + 4);
      } else {
        uq[nt][0] = make_float4(0,0,0,0); uq[nt][1] = make_float4(0,0,0,0);
      }
    }

    if (tt > 0){
      load_afrag(AtH, 0*4 + quad, m0, Ahb[0]);
      load_afrag(AtL, 0*4 + quad, m0, Alb[0]);
      #pragma unroll
      for (int kt = 0; kt < 8; ++kt){
        int cur = kt & 1;
        if (kt < 7){
          load_afrag(AtH, (kt+1)*4 + quad, m0, Ahb[cur^1]);
          load_afrag(AtL, (kt+1)*4 + quad, m0, Alb[cur^1]);
        }
        short8 Sbh[4], Sbl[4];
        #pragma unroll
        for (int nt = 0; nt < 4; ++nt){
          int off = ((kt*4 + quad)*64 + nt*16 + l16)*8;
          Sbh[nt] = *(const short8*)&StH[off];
          Sbl[nt] = *(const short8*)&StL[off];
        }
        #pragma unroll
        for (int mt = 0; mt < 4; ++mt)
          #pragma unroll
          for (int nt = 0; nt < 4; ++nt){
            acc[mt][nt] = __builtin_amdgcn_mfma_f32_16x16x32_bf16(Ahb[cur][mt], Sbh[nt], acc[mt][nt], 0,0,0);
            acc[mt][nt] = __builtin_amdgcn_mfma_f32_16x16x32_bf16(Ahb[cur][mt], Sbl[nt], acc[mt][nt], 0,0,0);
            acc[mt][nt] = __builtin_amdgcn_mfma_f32_16x16x32_bf16(Alb[cur][mt], Sbh[nt], acc[mt][nt], 0,0,0);
          }
      }
    }

    short8 uh[4], ul[4];
    #pragma unroll
    for (int nt = 0; nt < 4; ++nt){
      float v[8] = {uq[nt][0].x,uq[nt][0].y,uq[nt][0].z,uq[nt][0].w,
                    uq[nt][1].x,uq[nt][1].y,uq[nt][1].z,uq[nt][1].w};
      ushort_t hs[8], ls[8];
      #pragma unroll
      for (int j = 0; j < 8; ++j){
        hs[j] = f2bf(v[j]);
        ls[j] = f2bf(v[j] - bf2f(hs[j]));
      }
      uh[nt] = *(const short8*)hs; ul[nt] = *(const short8*)ls;
    }
    #pragma unroll
    for (int mt = 0; mt < 4; ++mt)
      #pragma unroll
      for (int nt = 0; nt < 4; ++nt){
        acc[mt][nt] = __builtin_amdgcn_mfma_f32_16x16x32_bf16(Bfh[mt], uh[nt], acc[mt][nt], 0,0,0);
        acc[mt][nt] = __builtin_amdgcn_mfma_f32_16x16x32_bf16(Bfh[mt], ul[nt], acc[mt][nt], 0,0,0);
        acc[mt][nt] = __builtin_amdgcn_mfma_f32_16x16x32_bf16(Bfl[mt], uh[nt], acc[mt][nt], 0,0,0);
      }

    __syncthreads();

    #pragma unroll
    for (int mt = 0; mt < 4; ++mt){
      int mb = mwave + mt*16 + quad*4;
      #pragma unroll
      for (int nt = 0; nt < 4; ++nt){
        int n = nt*16 + l16;
        f32x4 v = acc[mt][nt];
        *(float4*)&zout[((long)n*Tt + t)*Ll + mb] = make_float4(v[0],v[1],v[2],v[3]);
        if (tt == CC-1)
          *(float4*)&wend[((long)chunk*Bb + n)*Ll + mb] = make_float4(v[0],v[1],v[2],v[3]);
        #pragma unroll
        for (int reg = 0; reg < 4; ++reg){
          int m = mb + reg;
          ushort_t h = f2bf(v[reg]);
          ushort_t l = f2bf(v[reg] - bf2f(h));
          int so = ((m>>3)*64 + n)*8 + (m&7);
          StH[so] = h; StL[so] = l;
        }
        acc[mt][nt] = (f32x4){0.f,0.f,0.f,0.f};
      }
    }
    __syncthreads();
  }
}

// ---------------------------------------------------------------------------
// pass2 (MFMA, wide): boundary recurrence with split-bf16 MFMA.
// 512 threads = 8 waves; each wave owns 32 M-rows (mt<2). A-plane fragments
// are loop-invariant -> preloaded into registers ONCE (32 short8 = 128 VGPR).
// State in LDS fragments, layout ((m>>3)*64 + n)*8 + (m&7) (scan_mfma's).
// ---------------------------------------------------------------------------
__device__ __forceinline__ void frag_init_state512(
    const float* __restrict__ src, ushort_t* StH, ushort_t* StL, int tid)
{
  // src layout: src[n*256 + m]  (n = batch 0..63, m = latent 0..255)
  #pragma unroll
  for (int it = 0; it < 4; ++it){
    int idx = tid + it*512;        // 0..2047
    int m8 = idx >> 6, n = idx & 63;
    const float* p = src + (long)n*256 + m8*8;
    float4 v0 = *(const float4*)p;
    float4 v1 = *(const float4*)(p + 4);
    float vv[8] = {v0.x,v0.y,v0.z,v0.w,v1.x,v1.y,v1.z,v1.w};
    ushort_t hs[8], ls[8];
    #pragma unroll
    for (int j = 0; j < 8; ++j){
      hs[j] = f2bf(vv[j]);
      ls[j] = f2bf(vv[j] - bf2f(hs[j]));
    }
    *(uint4*)&StH[(m8*64 + n)*8] = *(const uint4*)hs;
    *(uint4*)&StL[(m8*64 + n)*8] = *(const uint4*)ls;
  }
}

__device__ __forceinline__ void p2_load_A(
    const ushort_t* __restrict__ PH, const ushort_t* __restrict__ PL,
    int wave, int lane, short8 Ah[2][8], short8 Al[2][8])
{
  int quad = lane >> 4, l16 = lane & 15;
  int m0 = wave*32 + l16;
  #pragma unroll
  for (int kt = 0; kt < 8; ++kt){
    int kq = kt*4 + quad;
    #pragma unroll
    for (int mt = 0; mt < 2; ++mt){
      Ah[mt][kt] = *(const short8*)&PH[((long)kq*256 + m0 + mt*16)*8];
      Al[mt][kt] = *(const short8*)&PL[((long)kq*256 + m0 + mt*16)*8];
    }
  }
}

// One recurrence step: St <- P^T @ St + addin ; optionally write fp32 result.
// addin/out layout: [n*256 + m].
__device__ __forceinline__ void p2_step_w(
    const short8 Ah[2][8], const short8 Al[2][8],
    const float* __restrict__ addin,
    ushort_t* StH, ushort_t* StL,
    float* __restrict__ out_f32,
    int wave, int lane)
{
  int quad = lane >> 4, l16 = lane & 15;
  int mwave = wave*32;

  f32x4 acc[2][4];
  #pragma unroll
  for (int mt = 0; mt < 2; ++mt){
    int mb = mwave + mt*16 + quad*4;
    #pragma unroll
    for (int nt = 0; nt < 4; ++nt){
      int n = nt*16 + l16;
      float4 v = *(const float4*)&addin[(long)n*256 + mb];
      acc[mt][nt] = (f32x4){v.x, v.y, v.z, v.w};
    }
  }

  #pragma unroll
  for (int kt = 0; kt < 8; ++kt){
    #pragma unroll
    for (int nt = 0; nt < 4; ++nt){
      int off = ((kt*4 + quad)*64 + nt*16 + l16)*8;
      short8 Sbh = *(const short8*)&StH[off];
      short8 Sbl = *(const short8*)&StL[off];
      #pragma unroll
      for (int mt = 0; mt < 2; ++mt){
        acc[mt][nt] = __builtin_amdgcn_mfma_f32_16x16x32_bf16(Ah[mt][kt], Sbh, acc[mt][nt], 0,0,0);
        acc[mt][nt] = __builtin_amdgcn_mfma_f32_16x16x32_bf16(Ah[mt][kt], Sbl, acc[mt][nt], 0,0,0);
        acc[mt][nt] = __builtin_amdgcn_mfma_f32_16x16x32_bf16(Al[mt][kt], Sbh, acc[mt][nt], 0,0,0);
      }
    }
  }

  __syncthreads();   // all waves done reading St

  #pragma unroll
  for (int mt = 0; mt < 2; ++mt){
    int mb = mwave + mt*16 + quad*4;
    #pragma unroll
    for (int nt = 0; nt < 4; ++nt){
      int n = nt*16 + l16;
      f32x4 v = acc[mt][nt];
      if (out_f32)
        *(float4*)&out_f32[(long)n*256 + mb] = make_float4(v[0],v[1],v[2],v[3]);
      #pragma unroll
      for (int reg = 0; reg < 4; ++reg){
        int m = mb + reg;
        ushort_t h = f2bf(v[reg]);
        int so = ((m>>3)*64 + n)*8 + (m&7);
        StH[so] = h;
        StL[so] = f2bf(v[reg] - bf2f(h));
      }
    }
  }
  __syncthreads();
}

// lend[s] = zero-init combine of wend[8s..8s+7] over A^8.  16 blocks.
__global__ __launch_bounds__(512) void pass2_local_mfma(
    const ushort_t* __restrict__ A8H, const ushort_t* __restrict__ A8L,
    const float* __restrict__ wend, float* __restrict__ lend)
{
  int s = blockIdx.x;
  int tid = threadIdx.x;
  int wave = tid >> 6, lane = tid & 63;
  __shared__ ushort_t StH[16384], StL[16384];
  short8 Ah[2][8], Al[2][8];
  p2_load_A(A8H, A8L, wave, lane, Ah, Al);
  frag_init_state512(wend + (long)(s*SC)*Bb*256, StH, StL, tid);
  __syncthreads();
  for (int i = 1; i < SC; ++i)
    p2_step_w(Ah, Al, wend + (long)(s*SC + i)*Bb*256, StH, StL,
              (i == SC-1) ? (lend + (long)s*Bb*256) : nullptr, wave, lane);
}

// Superchunk-level serial chain over A^64; writes inits at chunks (s+1)*8.
__global__ __launch_bounds__(512) void pass2_global_mfma(
    const ushort_t* __restrict__ A64H, const ushort_t* __restrict__ A64L,
    const float* __restrict__ lend, float* __restrict__ inits)
{
  int tid = threadIdx.x;
  int wave = tid >> 6, lane = tid & 63;
  __shared__ ushort_t StH[16384], StL[16384];
  short8 Ah[2][8], Al[2][8];
  p2_load_A(A64H, A64L, wave, lane, Ah, Al);
  frag_init_state512(inits, StH, StL, tid);   // chunk 0 = z0
  __syncthreads();
  for (int s = 0; s < NSC-1; ++s)
    p2_step_w(Ah, Al, lend + (long)s*Bb*256, StH, StL,
              inits + (long)((s+1)*SC)*Bb*256, wave, lane);
}

// Replay within each superchunk: fills inits at chunks 8s+1..8s+7.  16 blocks.
__global__ __launch_bounds__(512) void pass2_replay_mfma(
    const ushort_t* __restrict__ A8H, const ushort_t* __restrict__ A8L,
    const float* __restrict__ wend, float* __restrict__ inits)
{
  int s = blockIdx.x;
  int tid = threadIdx.x;
  int wave = tid >> 6, lane = tid & 63;
  __shared__ ushort_t StH[16384], StL[16384];
  short8 Ah[2][8], Al[2][8];
  p2_load_A(A8H, A8L, wave, lane, Ah, Al);
  frag_init_state512(inits + (long)(s*SC)*Bb*256, StH, StL, tid);
  __syncthreads();
  for (int i = 0; i < SC-1; ++i)
    p2_step_w(Ah, Al, wend + (long)(s*SC + i)*Bb*256, StH, StL,
              inits + (long)(s*SC + i + 1)*Bb*256, wave, lane);
}

// ---------------------------------------------------------------------------
// Correction GEMMs: out[b, c*CC+j, :] += inits[c*64+b] @ A^(j+1). Unchanged.
// ---------------------------------------------------------------------------
__global__ __launch_bounds__(256) void gemm_corr(
    const float* __restrict__ inits, const ushort_t* __restrict__ AjH,
    const ushort_t* __restrict__ AjL, float* __restrict__ out)
{
  int jz = blockIdx.z;
  const ushort_t* Whp = AjH + (long)jz*65536;
  const ushort_t* Wlp = AjL + (long)jz*65536;
  __shared__ __align__(16) ushort_t Xh[4*128*8], Xl[4*128*8];
  __shared__ __align__(16) ushort_t Wh[4*128*8], Wl[4*128*8];

  int tid  = threadIdx.x;
  int wave = tid >> 6, lane = tid & 63;
  int wm = wave & 1, wn = wave >> 1;
  int quad = lane >> 4, l16 = lane & 15;
  int row0 = blockIdx.y * 128;
  int col0 = blockIdx.x * 128;

  f32x4 acc[4][4];
  #pragma unroll
  for (int mt = 0; mt < 4; ++mt)
    #pragma unroll
    for (int nt = 0; nt < 4; ++nt) acc[mt][nt] = (f32x4){0.f,0.f,0.f,0.f};

  for (int kt = 0; kt < 8; ++kt){
    #pragma unroll
    for (int it = 0; it < 2; ++it){
      int idx = tid + it*256;
      int q = idx >> 7, m = idx & 127;
      const float* xp = &inits[(long)(row0 + m)*256 + kt*32 + q*8];
      float4 v0 = *(const float4*)xp;
      float4 v1 = *(const float4*)(xp + 4);
      float vv[8] = {v0.x,v0.y,v0.z,v0.w,v1.x,v1.y,v1.z,v1.w};
      ushort_t hs[8], ls[8];
      #pragma unroll
      for (int j = 0; j < 8; ++j){
        hs[j] = f2bf(vv[j]);
        ls[j] = f2bf(vv[j] - bf2f(hs[j]));
      }
      *(uint4*)&Xh[(q*128 + m)*8] = *(const uint4*)hs;
      *(uint4*)&Xl[(q*128 + m)*8] = *(const uint4*)ls;
      int n = idx & 127;
      long src = (long)(kt*4 + q)*256 + col0 + n;
      ((uint4*)Wh)[q*128 + n] = ((const uint4*)Whp)[src];
      ((uint4*)Wl)[q*128 + n] = ((const uint4*)Wlp)[src];
    }
    __syncthreads();
    short8 ah[4], al[4], bh[4], bl[4];
    #pragma unroll
    for (int mt = 0; mt < 4; ++mt){
      int off = (quad*128 + wm*64 + mt*16 + l16)*8;
      ah[mt] = *(const short8*)&Xh[off];
      al[mt] = *(const short8*)&Xl[off];
    }
    #pragma unroll
    for (int nt = 0; nt < 4; ++nt){
      int off = (quad*128 + wn*64 + nt*16 + l16)*8;
      bh[nt] = *(const short8*)&Wh[off];
      bl[nt] = *(const short8*)&Wl[off];
    }
    #pragma unroll
    for (int mt = 0; mt < 4; ++mt)
      #pragma unroll
      for (int nt = 0; nt < 4; ++nt){
        acc[mt][nt] = __builtin_amdgcn_mfma_f32_16x16x32_bf16(ah[mt], bh[nt], acc[mt][nt], 0,0,0);
        acc[mt][nt] = __builtin_amdgcn_mfma_f32_16x16x32_bf16(ah[mt], bl[nt], acc[mt][nt], 0,0,0);
        acc[mt][nt] = __builtin_amdgcn_mfma_f32_16x16x32_bf16(al[mt], bh[nt], acc[mt][nt], 0,0,0);
      }
    __syncthreads();
  }

  #pragma unroll
  for (int mt = 0; mt < 4; ++mt){
    #pragma unroll
    for (int nt = 0; nt < 4; ++nt){
      int col = col0 + wn*64 + nt*16 + l16;
      #pragma unroll
      for (int reg = 0; reg < 4; ++reg){
        int row = row0 + wm*64 + mt*16 + quad*4 + reg;
        int b = row & 63, c = row >> 6;
        int t = c*CC + jz;
        long addr = ((long)b*Tt + t)*Ll + col;
        out[addr] += acc[mt][nt][reg];
      }
    }
  }
}

// ---------------------------------------------------------------------------
// Decoder split-bf16 MFMA GEMM (unchanged; launched at 64x128).
// ---------------------------------------------------------------------------
template<int BM, int BN, bool INS, bool OUTS>
__global__ __launch_bounds__(256) void gemm_mfma(
    const float* __restrict__ X,
    const ushort_t* __restrict__ Xhp, const ushort_t* __restrict__ Xlp,
    const ushort_t* __restrict__ Whp, const ushort_t* __restrict__ Wlp,
    const float* __restrict__ bias, float* __restrict__ Y,
    ushort_t* __restrict__ Yh, ushort_t* __restrict__ Yl,
    int Mrows, int K, int N, int act)
{
  constexpr int BMh = BM/2, BNh = BN/2;
  constexpr int MT = BM/32, NT = BN/32;
  __shared__ __align__(16) ushort_t Xh[4*BM*8], Xl[4*BM*8];
  __shared__ __align__(16) ushort_t Wh[4*BN*8], Wl[4*BN*8];

  int tid  = threadIdx.x;
  int wave = tid >> 6, lane = tid & 63;
  int wm = wave & 1, wn = wave >> 1;
  int quad = lane >> 4, l16 = lane & 15;
  long row0 = (long)blockIdx.y * BM;
  int col0 = blockIdx.x * BN;

  f32x4 acc[MT][NT];
  #pragma unroll
  for (int mt = 0; mt < MT; ++mt)
    #pragma unroll
    for (int nt = 0; nt < NT; ++nt) acc[mt][nt] = (f32x4){0.f,0.f,0.f,0.f};

  for (int kt = 0; kt < K; kt += 32){
    int ktile = kt >> 5;
    if constexpr (INS){
      #pragma unroll
      for (int it = 0; it < (BM*4)/256; ++it){
        int idx = tid + it*256;
        int q = idx / BM, m = idx % BM;
        long src = (long)(ktile*4 + q)*Mrows + row0 + m;
        ((uint4*)Xh)[q*BM + m] = ((const uint4*)Xhp)[src];
        ((uint4*)Xl)[q*BM + m] = ((const uint4*)Xlp)[src];
      }
    } else {
      #pragma unroll
      for (int it = 0; it < (BM*4)/256; ++it){
        int idx = tid + it*256;
        int q = idx / BM, m = idx % BM;
        const float* xp = &X[(row0 + m)*(long)K + kt + q*8];
        float4 v0 = *(const float4*)xp;
        float4 v1 = *(const float4*)(xp + 4);
        float vv[8] = {v0.x,v0.y,v0.z,v0.w,v1.x,v1.y,v1.z,v1.w};
        ushort_t hs[8], ls[8];
        #pragma unroll
        for (int j = 0; j < 8; ++j){
          hs[j] = f2bf(vv[j]);
          ls[j] = f2bf(vv[j] - bf2f(hs[j]));
        }
        *(uint4*)&Xh[(q*BM + m)*8] = *(const uint4*)hs;
        *(uint4*)&Xl[(q*BM + m)*8] = *(const uint4*)ls;
      }
    }
    #pragma unroll
    for (int it = 0; it < (BN*4)/256; ++it){
      int idx = tid + it*256;
      int q = idx / BN, n = idx % BN;
      long src = (long)(ktile*4 + q)*N + col0 + n;
      ((uint4*)Wh)[q*BN + n] = ((const uint4*)Whp)[src];
      ((uint4*)Wl)[q*BN + n] = ((const uint4*)Wlp)[src];
    }
    __syncthreads();

    short8 ah[MT], al[MT], bh[NT], bl[NT];
    #pragma unroll
    for (int mt = 0; mt < MT; ++mt){
      int off = (quad*BM + wm*BMh + mt*16 + l16)*8;
      ah[mt] = *(const short8*)&Xh[off];
      al[mt] = *(const short8*)&Xl[off];
    }
    #pragma unroll
    for (int nt = 0; nt < NT; ++nt){
      int off = (quad*BN + wn*BNh + nt*16 + l16)*8;
      bh[nt] = *(const short8*)&Wh[off];
      bl[nt] = *(const short8*)&Wl[off];
    }
    #pragma unroll
    for (int mt = 0; mt < MT; ++mt)
      #pragma unroll
      for (int nt = 0; nt < NT; ++nt){
        acc[mt][nt] = __builtin_amdgcn_mfma_f32_16x16x32_bf16(ah[mt], bh[nt], acc[mt][nt], 0, 0, 0);
        acc[mt][nt] = __builtin_amdgcn_mfma_f32_16x16x32_bf16(ah[mt], bl[nt], acc[mt][nt], 0, 0, 0);
        acc[mt][nt] = __builtin_amdgcn_mfma_f32_16x16x32_bf16(al[mt], bh[nt], acc[mt][nt], 0, 0, 0);
      }
    __syncthreads();
  }

  #pragma unroll
  for (int mt = 0; mt < MT; ++mt){
    long rowb = row0 + wm*BMh + mt*16 + quad*4;
    #pragma unroll
    for (int nt = 0; nt < NT; ++nt){
      int col = col0 + wn*BNh + nt*16 + l16;
      float bs = bias[col];
      #pragma unroll
      for (int reg = 0; reg < 4; ++reg){
        float y = acc[mt][nt][reg] + bs;
        if (act) y = LKY(y);
        long row = rowb + reg;
        if constexpr (OUTS){
          ushort_t h = f2bf(y);
          ushort_t l = f2bf(y - bf2f(h));
          long off = ((long)(col >> 3)*Mrows + row)*8 + (col & 7);
          Yh[off] = h; Yl[off] = l;
        } else {
          Y[row*(long)N + col] = y;
        }
      }
    }
  }
}

// ---------------------------------------------------------------------------
extern "C" void kernel_launch(void* const* d_in, const int* in_sizes, int n_in,
                              void* d_out, int out_size, void* d_ws, size_t ws_size,
                              hipStream_t stream) {
  const float* in0    = (const float*)d_in[0];
  const float* enc_w1 = (const float*)d_in[1];
  const float* enc_b1 = (const float*)d_in[2];
  const float* enc_w2 = (const float*)d_in[3];
  const float* enc_b2 = (const float*)d_in[4];
  const float* enc_w3 = (const float*)d_in[5];
  const float* enc_b3 = (const float*)d_in[6];
  const float* A_w    = (const float*)d_in[7];
  const float* B_w    = (const float*)d_in[8];
  const float* dec_w1 = (const float*)d_in[9];
  const float* dec_b1 = (const float*)d_in[10];
  const float* dec_w2 = (const float*)d_in[11];
  const float* dec_b2 = (const float*)d_in[12];
  const float* dec_w3 = (const float*)d_in[13];
  const float* dec_b3 = (const float*)d_in[14];
  float* out = (float*)d_out;

  // ---- workspace layout (float slots); total 9,437,184 fl = 37.75 MB ----
  float* ws    = (float*)d_ws;
  float* h1enc = ws;                      // 32768
  float* h2enc = ws + 32768;              // 32768
  float* s2    = ws + 65536;              // A^2
  float* s3    = ws + 131072;             // A^3
  float* s4    = ws + 196608;             // A^4
  float* s8    = ws + 262144;             // A^8
  float* s16   = ws + 327680;
  float* s32   = ws + 393216;
  float* s64   = ws + 458752;             // A^64
  ushort_t* Whp_d = (ushort_t*)(ws + 524288);   // decoder W planes
  ushort_t* Wlp_d = (ushort_t*)(ws + 786432);
  float* Rf    = ws + 1048576;            // R-pool: 8,388,608 fl
  // scan-phase layout of R:
  ushort_t* AjH = (ushort_t*)Rf;                // 8 planes x 65536 ush
  ushort_t* AjL = (ushort_t*)(Rf + 262144);
  ushort_t* BtH = (ushort_t*)(Rf + 524288);     // 8192 ush
  ushort_t* BtL = BtH + 8192;
  float* wend  = Rf + 532480;             // 2,097,152
  float* inits = Rf + 2629632;            // 2,097,152 (inits[0] = z0)
  float* lend  = Rf + 4726784;            // 262,144 (ends at 4,988,928)
  ushort_t* A64H = (ushort_t*)(Rf + 4988928);   // 65536 ush (32768 fl)
  ushort_t* A64L = (ushort_t*)(Rf + 5021696);   // 65536 ush
  // decoder-phase aliases of R (scan data dead by then):
  ushort_t* h1h = (ushort_t*)Rf;
  ushort_t* h1l = (ushort_t*)(Rf + 2097152);
  ushort_t* h2h = (ushort_t*)(Rf + 4194304);
  ushort_t* h2l = (ushort_t*)(Rf + 6291456);
  // A^8 hi/lo planes in fragment order already exist: AjH/AjL plane 7.
  ushort_t* A8H = AjH + 7*65536;
  ushort_t* A8L = AjL + 7*65536;

  // Encoder (only t=0 feeds the scan) -> z0 into inits[0]
  enc_dense<<<dim3(64,16), 256, 0, stream>>>(in0, Tt*Dd, enc_w1, enc_b1, h1enc, 256, 512, 1);
  enc_dense<<<dim3(64,16), 256, 0, stream>>>(h1enc, 512, enc_w2, enc_b2, h2enc, 512, 512, 1);
  enc_dense<<<dim3(64, 8), 256, 0, stream>>>(h2enc, 512, enc_w3, enc_b3, inits, 512, 256, 1);

  // A^j planes (j=1..8) + A^64 planes for pass2
  prep_w<<<256, 256, 0, stream>>>(A_w, AjH, AjL, 256);                       // A^1 plane
  prep_bw<<<32, 256, 0, stream>>>(B_w, BtH, BtL);
  matmul_g<<<256, 256, 0, stream>>>(A_w, A_w, s2, AjH+1*65536, AjL+1*65536); // A^2
  matmul_g<<<256, 256, 0, stream>>>(s2, A_w, s3, AjH+2*65536, AjL+2*65536);  // A^3
  matmul_g<<<256, 256, 0, stream>>>(s2, s2, s4, AjH+3*65536, AjL+3*65536);   // A^4
  matmul_g<<<256, 256, 0, stream>>>(s4, A_w, nullptr, AjH+4*65536, AjL+4*65536); // A^5
  matmul_g<<<256, 256, 0, stream>>>(s4, s2, nullptr, AjH+5*65536, AjL+5*65536);  // A^6
  matmul_g<<<256, 256, 0, stream>>>(s4, s3, nullptr, AjH+6*65536, AjL+6*65536);  // A^7
  matmul_g<<<256, 256, 0, stream>>>(s4, s4, s8, A8H, A8L);                   // A^8 (+planes)
  matmul_g<<<256, 256, 0, stream>>>(s8, s8, s16, nullptr, nullptr);          // A^16
  matmul_g<<<256, 256, 0, stream>>>(s16, s16, s32, nullptr, nullptr);        // A^32
  matmul_g<<<256, 256, 0, stream>>>(s32, s32, s64, A64H, A64L);              // A^64 (+planes)

  // Decoder weight planes
  prep_w<<<512,  256, 0, stream>>>(dec_w1, Whp_d,          Wlp_d,          512);
  prep_w<<<1024, 256, 0, stream>>>(dec_w2, Whp_d + 131072, Wlp_d + 131072, 512);
  prep_w<<<512,  256, 0, stream>>>(dec_w3, Whp_d + 393216, Wlp_d + 393216, 256);

  // Pass 1: MFMA zero-init chunk scans; w[t] -> d_out, ends -> wend
  scan_mfma<<<NCh, 256, 0, stream>>>(in0, AjH, AjL, BtH, BtL, wend, out);
  // Pass 2: hierarchical boundary recurrence, split-bf16 MFMA, wide blocks
  pass2_local_mfma <<<NSC, 512, 0, stream>>>(A8H, A8L, wend, lend);
  pass2_global_mfma<<<1,   512, 0, stream>>>(A64H, A64L, lend, inits);
  pass2_replay_mfma<<<NSC, 512, 0, stream>>>(A8H, A8L, wend, inits);
  // Pass 3 (parallel corrections): out[b, c*8+j, :] += inits[c] @ A^(j+1)
  gemm_corr<<<dim3(2, 64, 8), 256, 0, stream>>>(inits, AjH, AjL, out);

  // Decoder: 3-layer MLP, split-bf16 MFMA, 64x128 tiles
  for (int rc = 0; rc < DEC_CHUNKS; ++rc){
    const float* zc = out + (long)rc*DEC_ROWS*Ll;
    float* oc       = out + (long)rc*DEC_ROWS*Ll;
    gemm_mfma<64,128,false,true><<<dim3(Ee/128, DEC_ROWS/64), 256, 0, stream>>>(
        zc, nullptr, nullptr, Whp_d, Wlp_d, dec_b1, nullptr, h1h, h1l, DEC_ROWS, Ll, Ee, 1);
    gemm_mfma<64,128,true,true><<<dim3(Ee/128, DEC_ROWS/64), 256, 0, stream>>>(
        nullptr, h1h, h1l, Whp_d + 131072, Wlp_d + 131072, dec_b2, nullptr, h2h, h2l, DEC_ROWS, Ee, Ee, 1);
    gemm_mfma<64,128,true,false><<<dim3(Ss/128, DEC_ROWS/64), 256, 0, stream>>>(
        nullptr, h2h, h2l, Whp_d + 393216, Wlp_d + 393216, dec_b3, oc, nullptr, nullptr, DEC_ROWS, Ee, Ss, 0);
  }
}

// Round 3
// 984.539 us; speedup vs baseline: 1.0558x; 1.0225x over previous
//
#include <hip/hip_runtime.h>

// Problem dims
constexpr int Bb  = 64;      // batch
constexpr int Tt  = 1024;    // time
constexpr int Dd  = 288;     // padded input feature dim
constexpr int Ss  = 256;     // STATE_DIM
constexpr int ALa = 16;      // ACT_LEN
constexpr int Ll  = 256;     // LATENT
constexpr int Ee  = 512;     // ENC
constexpr int CC  = 8;       // scan chunk length
constexpr int NCh = 128;     // number of chunks (CC*NCh == Tt)
constexpr int NSC = 16;      // superchunks for boundary recurrence
constexpr int SC  = 8;       // chunk-boundaries per superchunk
constexpr int DEC_CHUNKS = 8;
constexpr int DEC_ROWS = (Bb*Tt)/DEC_CHUNKS;  // 8192 rows per chunk

#define LKY(v) ((v) >= 0.f ? (v) : 0.01f*(v))

using f32x4  = __attribute__((ext_vector_type(4))) float;
using short8 = __attribute__((ext_vector_type(8))) short;
typedef unsigned short ushort_t;

__device__ __forceinline__ unsigned short f2bf(float f){
  unsigned int u = __float_as_uint(f);
  u = (u + 0x7fffu + ((u >> 16) & 1u)) >> 16;   // RNE
  return (unsigned short)u;
}
__device__ __forceinline__ float bf2f(unsigned short h){
  return __uint_as_float(((unsigned int)h) << 16);
}

// ---------------------------------------------------------------------------
// Encoder dense layer, split-K: grid (row, N/32); 256 thr = 32 cols x 8 kslc.
// ---------------------------------------------------------------------------
__global__ __launch_bounds__(256) void enc_dense(
    const float* __restrict__ xin, int xstride,
    const float* __restrict__ W, const float* __restrict__ bias,
    float* __restrict__ out, int K, int N, int act)
{
  int b = blockIdx.x, col0 = blockIdx.y * 32;
  int tid = threadIdx.x;
  int tx = tid & 31, tk = tid >> 5;
  __shared__ float x[512];
  __shared__ float part[8][33];
  for (int k = tid; k < K; k += 256) x[k] = xin[(long)b*xstride + k];
  __syncthreads();
  int j = col0 + tx;
  float p0=0.f,p1=0.f,p2=0.f,p3=0.f;
  int iters = K >> 3;
  #pragma unroll 2
  for (int i = 0; i < iters; i += 4){
    int k0 = tk + 8*i;
    p0 = fmaf(x[k0     ], W[(long)(k0     )*N + j], p0);
    p1 = fmaf(x[k0 +  8], W[(long)(k0 +  8)*N + j], p1);
    p2 = fmaf(x[k0 + 16], W[(long)(k0 + 16)*N + j], p2);
    p3 = fmaf(x[k0 + 24], W[(long)(k0 + 24)*N + j], p3);
  }
  part[tk][tx] = (p0+p1)+(p2+p3);
  __syncthreads();
  if (tid < 32){
    float s = part[0][tid];
    #pragma unroll
    for (int q = 1; q < 8; ++q) s += part[q][tid];
    s += bias[col0 + tid];
    out[b*N + col0 + tid] = act ? LKY(s) : s;
  }
}

// ---------------------------------------------------------------------------
// 256x256 matmul C = X @ Y, split-K: block = row; 256 thr = 64 j4-groups x 4 kslc.
// Optional fp32 out + split planes ((k>>3)*256+n)*8+(k&7).
// ---------------------------------------------------------------------------
__global__ __launch_bounds__(256) void matmul_g(
    const float* __restrict__ X, const float* __restrict__ Y,
    float* __restrict__ Cf, ushort_t* __restrict__ Ch, ushort_t* __restrict__ Cl)
{
  int i = blockIdx.x;
  int tid = threadIdx.x;
  int jg = tid & 63, tk = tid >> 6;
  __shared__ float row[256];
  __shared__ float4 part[4][64];
  if (tid < 256) row[tid] = X[i*256 + tid];
  __syncthreads();
  int j4 = jg*4;
  float4 p0 = make_float4(0,0,0,0), p1 = make_float4(0,0,0,0);
  int kb = tk*64;
  #pragma unroll 4
  for (int k = kb; k < kb+64; k += 2){
    float x0 = row[k], x1 = row[k+1];
    float4 y0 = *(const float4*)&Y[(k  )*256 + j4];
    float4 y1 = *(const float4*)&Y[(k+1)*256 + j4];
    p0.x = fmaf(x0,y0.x,p0.x); p0.y = fmaf(x0,y0.y,p0.y);
    p0.z = fmaf(x0,y0.z,p0.z); p0.w = fmaf(x0,y0.w,p0.w);
    p1.x = fmaf(x1,y1.x,p1.x); p1.y = fmaf(x1,y1.y,p1.y);
    p1.z = fmaf(x1,y1.z,p1.z); p1.w = fmaf(x1,y1.w,p1.w);
  }
  p0.x+=p1.x; p0.y+=p1.y; p0.z+=p1.z; p0.w+=p1.w;
  part[tk][jg] = p0;
  __syncthreads();
  if (tid < 64){
    float4 s = part[0][tid];
    #pragma unroll
    for (int q = 1; q < 4; ++q){
      float4 v = part[q][tid];
      s.x+=v.x; s.y+=v.y; s.z+=v.z; s.w+=v.w;
    }
    int j = tid*4;
    if (Cf) *(float4*)&Cf[i*256 + j] = s;
    if (Ch){
      float vv[4] = {s.x,s.y,s.z,s.w};
      #pragma unroll
      for (int e = 0; e < 4; ++e){
        ushort_t h = f2bf(vv[e]);
        int o = ((i>>3)*256 + j + e)*8 + (i&7);
        Ch[o] = h; Cl[o] = f2bf(vv[e] - bf2f(h));
      }
    }
  }
}

// ---------------------------------------------------------------------------
// Split fp32 weight matrix (KxN) into hi/lo bf16 planes in fragment order.
// ---------------------------------------------------------------------------
__global__ __launch_bounds__(256) void prep_w(
    const float* __restrict__ W, ushort_t* __restrict__ Wh,
    ushort_t* __restrict__ Wl, int N)
{
  int o = blockIdx.x*256 + threadIdx.x;
  int j = o & 7;
  int rest = o >> 3;
  int n = rest % N;
  int t8 = rest / N;
  int k = t8*8 + j;
  float v = W[k*N + n];
  ushort_t h = f2bf(v);
  Wh[o] = h;
  Wl[o] = f2bf(v - bf2f(h));
}

// ---------------------------------------------------------------------------
// B_w^T plane for the scan's u-term: K padded 16->32 (zeros), N=256.
// ---------------------------------------------------------------------------
__global__ __launch_bounds__(256) void prep_bw(
    const float* __restrict__ B, ushort_t* __restrict__ Bh, ushort_t* __restrict__ Bl)
{
  int o = blockIdx.x*256 + threadIdx.x;     // 8192 total
  int j = o & 7, rest = o >> 3;
  int n = rest & 255, kq = rest >> 8;
  int k = kq*8 + j;
  float v = (k < ALa) ? B[k*256 + n] : 0.f;
  ushort_t h = f2bf(v);
  Bh[o] = h; Bl[o] = f2bf(v - bf2f(h));
}

// ---------------------------------------------------------------------------
// MFMA chunk scan (zero-init pass). Unchanged (known-good).
// ---------------------------------------------------------------------------
__device__ __forceinline__ void load_afrag(
    const ushort_t* __restrict__ P, int kq, int m0, short8* dst)
{
  #pragma unroll
  for (int mt = 0; mt < 4; ++mt)
    dst[mt] = *(const short8*)&P[((long)kq*256 + m0 + mt*16)*8];
}

__global__ __launch_bounds__(256) void scan_mfma(
    const float* __restrict__ in0,
    const ushort_t* __restrict__ AtH, const ushort_t* __restrict__ AtL,
    const ushort_t* __restrict__ BtH, const ushort_t* __restrict__ BtL,
    float* __restrict__ wend, float* __restrict__ zout)
{
  int chunk = blockIdx.x;
  int tid = threadIdx.x;
  int wave = tid >> 6, lane = tid & 63;
  int quad = lane >> 4, l16 = lane & 15;
  int mwave = wave * 64;
  int m0 = mwave + l16;

  __shared__ ushort_t StH[16384];
  __shared__ ushort_t StL[16384];

  short8 Bfh[4], Bfl[4];
  #pragma unroll
  for (int mt = 0; mt < 4; ++mt){
    int off = ((quad)*256 + m0 + mt*16)*8;
    Bfh[mt] = *(const short8*)&BtH[off];
    Bfl[mt] = *(const short8*)&BtL[off];
  }

  f32x4 acc[4][4];
  #pragma unroll
  for (int mt = 0; mt < 4; ++mt)
    #pragma unroll
    for (int nt = 0; nt < 4; ++nt) acc[mt][nt] = (f32x4){0.f,0.f,0.f,0.f};

  const float* ubase[4];
  #pragma unroll
  for (int nt = 0; nt < 4; ++nt)
    ubase[nt] = in0 + (long)(nt*16 + l16)*(Tt*Dd) + (Ss + ALa) + quad*8;

  short8 Ahb[2][4], Alb[2][4];

  for (int tt = 0; tt < CC; ++tt){
    int t = chunk*CC + tt;
    float4 uq[4][2];
    #pragma unroll
    for (int nt = 0; nt < 4; ++nt){
      if (quad < 2){
        const float* up = ubase[nt] + (long)t*Dd;
        uq[nt][0] = *(const float4*)up;
        uq[nt][1] = *(const float4*)(up + 4);
      } else {
        uq[nt][0] = make_float4(0,0,0,0); uq[nt][1] = make_float4(0,0,0,0);
      }
    }

    if (tt > 0){
      load_afrag(AtH, 0*4 + quad, m0, Ahb[0]);
      load_afrag(AtL, 0*4 + quad, m0, Alb[0]);
      #pragma unroll
      for (int kt = 0; kt < 8; ++kt){
        int cur = kt & 1;
        if (kt < 7){
          load_afrag(AtH, (kt+1)*4 + quad, m0, Ahb[cur^1]);
          load_afrag(AtL, (kt+1)*4 + quad, m0, Alb[cur^1]);
        }
        short8 Sbh[4], Sbl[4];
        #pragma unroll
        for (int nt = 0; nt < 4; ++nt){
          int off = ((kt*4 + quad)*64 + nt*16 + l16)*8;
          Sbh[nt] = *(const short8*)&StH[off];
          Sbl[nt] = *(const short8*)&StL[off];
        }
        #pragma unroll
        for (int mt = 0; mt < 4; ++mt)
          #pragma unroll
          for (int nt = 0; nt < 4; ++nt){
            acc[mt][nt] = __builtin_amdgcn_mfma_f32_16x16x32_bf16(Ahb[cur][mt], Sbh[nt], acc[mt][nt], 0,0,0);
            acc[mt][nt] = __builtin_amdgcn_mfma_f32_16x16x32_bf16(Ahb[cur][mt], Sbl[nt], acc[mt][nt], 0,0,0);
            acc[mt][nt] = __builtin_amdgcn_mfma_f32_16x16x32_bf16(Alb[cur][mt], Sbh[nt], acc[mt][nt], 0,0,0);
          }
      }
    }

    short8 uh[4], ul[4];
    #pragma unroll
    for (int nt = 0; nt < 4; ++nt){
      float v[8] = {uq[nt][0].x,uq[nt][0].y,uq[nt][0].z,uq[nt][0].w,
                    uq[nt][1].x,uq[nt][1].y,uq[nt][1].z,uq[nt][1].w};
      ushort_t hs[8], ls[8];
      #pragma unroll
      for (int j = 0; j < 8; ++j){
        hs[j] = f2bf(v[j]);
        ls[j] = f2bf(v[j] - bf2f(hs[j]));
      }
      uh[nt] = *(const short8*)hs; ul[nt] = *(const short8*)ls;
    }
    #pragma unroll
    for (int mt = 0; mt < 4; ++mt)
      #pragma unroll
      for (int nt = 0; nt < 4; ++nt){
        acc[mt][nt] = __builtin_amdgcn_mfma_f32_16x16x32_bf16(Bfh[mt], uh[nt], acc[mt][nt], 0,0,0);
        acc[mt][nt] = __builtin_amdgcn_mfma_f32_16x16x32_bf16(Bfh[mt], ul[nt], acc[mt][nt], 0,0,0);
        acc[mt][nt] = __builtin_amdgcn_mfma_f32_16x16x32_bf16(Bfl[mt], uh[nt], acc[mt][nt], 0,0,0);
      }

    __syncthreads();

    #pragma unroll
    for (int mt = 0; mt < 4; ++mt){
      int mb = mwave + mt*16 + quad*4;
      #pragma unroll
      for (int nt = 0; nt < 4; ++nt){
        int n = nt*16 + l16;
        f32x4 v = acc[mt][nt];
        *(float4*)&zout[((long)n*Tt + t)*Ll + mb] = make_float4(v[0],v[1],v[2],v[3]);
        if (tt == CC-1)
          *(float4*)&wend[((long)chunk*Bb + n)*Ll + mb] = make_float4(v[0],v[1],v[2],v[3]);
        #pragma unroll
        for (int reg = 0; reg < 4; ++reg){
          int m = mb + reg;
          ushort_t h = f2bf(v[reg]);
          ushort_t l = f2bf(v[reg] - bf2f(h));
          int so = ((m>>3)*64 + n)*8 + (m&7);
          StH[so] = h; StL[so] = l;
        }
        acc[mt][nt] = (f32x4){0.f,0.f,0.f,0.f};
      }
    }
    __syncthreads();
  }
}

// ---------------------------------------------------------------------------
// pass2 (Kogge-Stone MFMA): boundary recurrence via parallel prefix-doubling.
// State tiles are 64x256 fp32 [n*256 + m]. One GEMM body per block:
//   out = accsrc + bsrc @ P   (P given as hi/lo bf16 planes, M=latent mapping)
// 512 threads = 8 waves, each wave owns 32 M-rows; A planes preloaded to regs.
// ---------------------------------------------------------------------------
__device__ __forceinline__ void frag_init_state512(
    const float* __restrict__ src, ushort_t* StH, ushort_t* StL, int tid)
{
  // src layout: src[n*256 + m]  (n = batch 0..63, m = latent 0..255)
  #pragma unroll
  for (int it = 0; it < 4; ++it){
    int idx = tid + it*512;        // 0..2047
    int m8 = idx >> 6, n = idx & 63;
    const float* p = src + (long)n*256 + m8*8;
    float4 v0 = *(const float4*)p;
    float4 v1 = *(const float4*)(p + 4);
    float vv[8] = {v0.x,v0.y,v0.z,v0.w,v1.x,v1.y,v1.z,v1.w};
    ushort_t hs[8], ls[8];
    #pragma unroll
    for (int j = 0; j < 8; ++j){
      hs[j] = f2bf(vv[j]);
      ls[j] = f2bf(vv[j] - bf2f(hs[j]));
    }
    *(uint4*)&StH[(m8*64 + n)*8] = *(const uint4*)hs;
    *(uint4*)&StL[(m8*64 + n)*8] = *(const uint4*)ls;
  }
}

__device__ __forceinline__ void p2_load_A(
    const ushort_t* __restrict__ PH, const ushort_t* __restrict__ PL,
    int wave, int lane, short8 Ah[2][8], short8 Al[2][8])
{
  int quad = lane >> 4, l16 = lane & 15;
  int m0 = wave*32 + l16;
  #pragma unroll
  for (int kt = 0; kt < 8; ++kt){
    int kq = kt*4 + quad;
    #pragma unroll
    for (int mt = 0; mt < 2; ++mt){
      Ah[mt][kt] = *(const short8*)&PH[((long)kq*256 + m0 + mt*16)*8];
      Al[mt][kt] = *(const short8*)&PL[((long)kq*256 + m0 + mt*16)*8];
    }
  }
}

// out = accsrc + bsrc @ P  (single barrier; no LDS writeback)
__device__ __forceinline__ void ks_gemm_body(
    const ushort_t* __restrict__ PH, const ushort_t* __restrict__ PL,
    const float* __restrict__ accsrc, const float* __restrict__ bsrc,
    float* __restrict__ outp, ushort_t* StH, ushort_t* StL)
{
  int tid = threadIdx.x;
  int wave = tid >> 6, lane = tid & 63;
  int quad = lane >> 4, l16 = lane & 15;
  int mwave = wave*32;

  short8 Ah[2][8], Al[2][8];
  p2_load_A(PH, PL, wave, lane, Ah, Al);
  frag_init_state512(bsrc, StH, StL, tid);

  f32x4 acc[2][4];
  #pragma unroll
  for (int mt = 0; mt < 2; ++mt){
    int mb = mwave + mt*16 + quad*4;
    #pragma unroll
    for (int nt = 0; nt < 4; ++nt){
      int n = nt*16 + l16;
      float4 v = *(const float4*)&accsrc[(long)n*256 + mb];
      acc[mt][nt] = (f32x4){v.x, v.y, v.z, v.w};
    }
  }
  __syncthreads();

  #pragma unroll
  for (int kt = 0; kt < 8; ++kt){
    #pragma unroll
    for (int nt = 0; nt < 4; ++nt){
      int off = ((kt*4 + quad)*64 + nt*16 + l16)*8;
      short8 Sbh = *(const short8*)&StH[off];
      short8 Sbl = *(const short8*)&StL[off];
      #pragma unroll
      for (int mt = 0; mt < 2; ++mt){
        acc[mt][nt] = __builtin_amdgcn_mfma_f32_16x16x32_bf16(Ah[mt][kt], Sbh, acc[mt][nt], 0,0,0);
        acc[mt][nt] = __builtin_amdgcn_mfma_f32_16x16x32_bf16(Ah[mt][kt], Sbl, acc[mt][nt], 0,0,0);
        acc[mt][nt] = __builtin_amdgcn_mfma_f32_16x16x32_bf16(Al[mt][kt], Sbh, acc[mt][nt], 0,0,0);
      }
    }
  }

  #pragma unroll
  for (int mt = 0; mt < 2; ++mt){
    int mb = mwave + mt*16 + quad*4;
    #pragma unroll
    for (int nt = 0; nt < 4; ++nt){
      int n = nt*16 + l16;
      f32x4 v = acc[mt][nt];
      *(float4*)&outp[(long)n*256 + mb] = make_float4(v[0],v[1],v[2],v[3]);
    }
  }
}

// Source resolver for KS-global round 1 (virtual init sequence):
//   x[0] = z0, x[c] = LS[8c-1] (superchunk-local full prefix end).
__device__ __forceinline__ const float* ks_src(
    const float* __restrict__ in, const float* __restrict__ z0,
    const float* __restrict__ pbend, int c, int init_mode)
{
  if (!init_mode) return in + (long)c*(Bb*Ll);
  return (c == 0) ? z0 : (pbend + (long)(8*c - 1)*(Bb*Ll));
}

// One Kogge-Stone round: out[c] = in[c] + in[c-d] @ P  (or copy if below d
// within its segment). local_seg=1: 8-chunk segments; else global sequence.
__global__ __launch_bounds__(512) void ks_round(
    const ushort_t* __restrict__ PH, const ushort_t* __restrict__ PL,
    const float* __restrict__ in, const float* __restrict__ z0,
    const float* __restrict__ pbend,
    float* __restrict__ out, long outStride, int d, int local_seg, int init_mode)
{
  int c = blockIdx.x;
  int tid = threadIdx.x;
  int pos = local_seg ? (c & 7) : c;
  const float* src_c = ks_src(in, z0, pbend, c, init_mode);
  float* op = out + (long)c*outStride;

  if (pos < d){
    const float4* s4p = (const float4*)src_c;
    float4* d4p = (float4*)op;
    #pragma unroll
    for (int it = 0; it < 8; ++it) d4p[tid + it*512] = s4p[tid + it*512];
    return;
  }
  const float* src_cd = ks_src(in, z0, pbend, c - d, init_mode);
  __shared__ ushort_t StH[16384], StL[16384];
  ks_gemm_body(PH, PL, src_c, src_cd, op, StH, StL);
}

// Parallel replay correction: inits[8s+i] = LS[8s+i-1] + h[s] @ A8^i,
// h[s] = inits[8s] (written by KS-global final round). Grid (i-1, s).
__global__ __launch_bounds__(512) void replay_corr(
    const ushort_t* __restrict__ A8PH, const ushort_t* __restrict__ A8PL,
    const float* __restrict__ pb, float* __restrict__ inits)
{
  int i = blockIdx.x + 1;     // 1..7
  int s = blockIdx.y;         // 0..15
  __shared__ ushort_t StH[16384], StL[16384];
  ks_gemm_body(A8PH + (long)(i-1)*65536, A8PL + (long)(i-1)*65536,
               pb + (long)(8*s + i - 1)*(Bb*Ll),
               inits + (long)(8*s)*(Bb*Ll),
               inits + (long)(8*s + i)*(Bb*Ll), StH, StL);
}

// ---------------------------------------------------------------------------
// Correction GEMMs: out[b, c*CC+j, :] += inits[c*64+b] @ A^(j+1). Unchanged.
// ---------------------------------------------------------------------------
__global__ __launch_bounds__(256) void gemm_corr(
    const float* __restrict__ inits, const ushort_t* __restrict__ AjH,
    const ushort_t* __restrict__ AjL, float* __restrict__ out)
{
  int jz = blockIdx.z;
  const ushort_t* Whp = AjH + (long)jz*65536;
  const ushort_t* Wlp = AjL + (long)jz*65536;
  __shared__ __align__(16) ushort_t Xh[4*128*8], Xl[4*128*8];
  __shared__ __align__(16) ushort_t Wh[4*128*8], Wl[4*128*8];

  int tid  = threadIdx.x;
  int wave = tid >> 6, lane = tid & 63;
  int wm = wave & 1, wn = wave >> 1;
  int quad = lane >> 4, l16 = lane & 15;
  int row0 = blockIdx.y * 128;
  int col0 = blockIdx.x * 128;

  f32x4 acc[4][4];
  #pragma unroll
  for (int mt = 0; mt < 4; ++mt)
    #pragma unroll
    for (int nt = 0; nt < 4; ++nt) acc[mt][nt] = (f32x4){0.f,0.f,0.f,0.f};

  for (int kt = 0; kt < 8; ++kt){
    #pragma unroll
    for (int it = 0; it < 2; ++it){
      int idx = tid + it*256;
      int q = idx >> 7, m = idx & 127;
      const float* xp = &inits[(long)(row0 + m)*256 + kt*32 + q*8];
      float4 v0 = *(const float4*)xp;
      float4 v1 = *(const float4*)(xp + 4);
      float vv[8] = {v0.x,v0.y,v0.z,v0.w,v1.x,v1.y,v1.z,v1.w};
      ushort_t hs[8], ls[8];
      #pragma unroll
      for (int j = 0; j < 8; ++j){
        hs[j] = f2bf(vv[j]);
        ls[j] = f2bf(vv[j] - bf2f(hs[j]));
      }
      *(uint4*)&Xh[(q*128 + m)*8] = *(const uint4*)hs;
      *(uint4*)&Xl[(q*128 + m)*8] = *(const uint4*)ls;
      int n = idx & 127;
      long src = (long)(kt*4 + q)*256 + col0 + n;
      ((uint4*)Wh)[q*128 + n] = ((const uint4*)Whp)[src];
      ((uint4*)Wl)[q*128 + n] = ((const uint4*)Wlp)[src];
    }
    __syncthreads();
    short8 ah[4], al[4], bh[4], bl[4];
    #pragma unroll
    for (int mt = 0; mt < 4; ++mt){
      int off = (quad*128 + wm*64 + mt*16 + l16)*8;
      ah[mt] = *(const short8*)&Xh[off];
      al[mt] = *(const short8*)&Xl[off];
    }
    #pragma unroll
    for (int nt = 0; nt < 4; ++nt){
      int off = (quad*128 + wn*64 + nt*16 + l16)*8;
      bh[nt] = *(const short8*)&Wh[off];
      bl[nt] = *(const short8*)&Wl[off];
    }
    #pragma unroll
    for (int mt = 0; mt < 4; ++mt)
      #pragma unroll
      for (int nt = 0; nt < 4; ++nt){
        acc[mt][nt] = __builtin_amdgcn_mfma_f32_16x16x32_bf16(ah[mt], bh[nt], acc[mt][nt], 0,0,0);
        acc[mt][nt] = __builtin_amdgcn_mfma_f32_16x16x32_bf16(ah[mt], bl[nt], acc[mt][nt], 0,0,0);
        acc[mt][nt] = __builtin_amdgcn_mfma_f32_16x16x32_bf16(al[mt], bh[nt], acc[mt][nt], 0,0,0);
      }
    __syncthreads();
  }

  #pragma unroll
  for (int mt = 0; mt < 4; ++mt){
    #pragma unroll
    for (int nt = 0; nt < 4; ++nt){
      int col = col0 + wn*64 + nt*16 + l16;
      #pragma unroll
      for (int reg = 0; reg < 4; ++reg){
        int row = row0 + wm*64 + mt*16 + quad*4 + reg;
        int b = row & 63, c = row >> 6;
        int t = c*CC + jz;
        long addr = ((long)b*Tt + t)*Ll + col;
        out[addr] += acc[mt][nt][reg];
      }
    }
  }
}

// ---------------------------------------------------------------------------
// Decoder split-bf16 MFMA GEMM (unchanged; launched at 64x128).
// ---------------------------------------------------------------------------
template<int BM, int BN, bool INS, bool OUTS>
__global__ __launch_bounds__(256) void gemm_mfma(
    const float* __restrict__ X,
    const ushort_t* __restrict__ Xhp, const ushort_t* __restrict__ Xlp,
    const ushort_t* __restrict__ Whp, const ushort_t* __restrict__ Wlp,
    const float* __restrict__ bias, float* __restrict__ Y,
    ushort_t* __restrict__ Yh, ushort_t* __restrict__ Yl,
    int Mrows, int K, int N, int act)
{
  constexpr int BMh = BM/2, BNh = BN/2;
  constexpr int MT = BM/32, NT = BN/32;
  __shared__ __align__(16) ushort_t Xh[4*BM*8], Xl[4*BM*8];
  __shared__ __align__(16) ushort_t Wh[4*BN*8], Wl[4*BN*8];

  int tid  = threadIdx.x;
  int wave = tid >> 6, lane = tid & 63;
  int wm = wave & 1, wn = wave >> 1;
  int quad = lane >> 4, l16 = lane & 15;
  long row0 = (long)blockIdx.y * BM;
  int col0 = blockIdx.x * BN;

  f32x4 acc[MT][NT];
  #pragma unroll
  for (int mt = 0; mt < MT; ++mt)
    #pragma unroll
    for (int nt = 0; nt < NT; ++nt) acc[mt][nt] = (f32x4){0.f,0.f,0.f,0.f};

  for (int kt = 0; kt < K; kt += 32){
    int ktile = kt >> 5;
    if constexpr (INS){
      #pragma unroll
      for (int it = 0; it < (BM*4)/256; ++it){
        int idx = tid + it*256;
        int q = idx / BM, m = idx % BM;
        long src = (long)(ktile*4 + q)*Mrows + row0 + m;
        ((uint4*)Xh)[q*BM + m] = ((const uint4*)Xhp)[src];
        ((uint4*)Xl)[q*BM + m] = ((const uint4*)Xlp)[src];
      }
    } else {
      #pragma unroll
      for (int it = 0; it < (BM*4)/256; ++it){
        int idx = tid + it*256;
        int q = idx / BM, m = idx % BM;
        const float* xp = &X[(row0 + m)*(long)K + kt + q*8];
        float4 v0 = *(const float4*)xp;
        float4 v1 = *(const float4*)(xp + 4);
        float vv[8] = {v0.x,v0.y,v0.z,v0.w,v1.x,v1.y,v1.z,v1.w};
        ushort_t hs[8], ls[8];
        #pragma unroll
        for (int j = 0; j < 8; ++j){
          hs[j] = f2bf(vv[j]);
          ls[j] = f2bf(vv[j] - bf2f(hs[j]));
        }
        *(uint4*)&Xh[(q*BM + m)*8] = *(const uint4*)hs;
        *(uint4*)&Xl[(q*BM + m)*8] = *(const uint4*)ls;
      }
    }
    #pragma unroll
    for (int it = 0; it < (BN*4)/256; ++it){
      int idx = tid + it*256;
      int q = idx / BN, n = idx % BN;
      long src = (long)(ktile*4 + q)*N + col0 + n;
      ((uint4*)Wh)[q*BN + n] = ((const uint4*)Whp)[src];
      ((uint4*)Wl)[q*BN + n] = ((const uint4*)Wlp)[src];
    }
    __syncthreads();

    short8 ah[MT], al[MT], bh[NT], bl[NT];
    #pragma unroll
    for (int mt = 0; mt < MT; ++mt){
      int off = (quad*BM + wm*BMh + mt*16 + l16)*8;
      ah[mt] = *(const short8*)&Xh[off];
      al[mt] = *(const short8*)&Xl[off];
    }
    #pragma unroll
    for (int nt = 0; nt < NT; ++nt){
      int off = (quad*BN + wn*BNh + nt*16 + l16)*8;
      bh[nt] = *(const short8*)&Wh[off];
      bl[nt] = *(const short8*)&Wl[off];
    }
    #pragma unroll
    for (int mt = 0; mt < MT; ++mt)
      #pragma unroll
      for (int nt = 0; nt < NT; ++nt){
        acc[mt][nt] = __builtin_amdgcn_mfma_f32_16x16x32_bf16(ah[mt], bh[nt], acc[mt][nt], 0, 0, 0);
        acc[mt][nt] = __builtin_amdgcn_mfma_f32_16x16x32_bf16(ah[mt], bl[nt], acc[mt][nt], 0, 0, 0);
        acc[mt][nt] = __builtin_amdgcn_mfma_f32_16x16x32_bf16(al[mt], bh[nt], acc[mt][nt], 0, 0, 0);
      }
    __syncthreads();
  }

  #pragma unroll
  for (int mt = 0; mt < MT; ++mt){
    long rowb = row0 + wm*BMh + mt*16 + quad*4;
    #pragma unroll
    for (int nt = 0; nt < NT; ++nt){
      int col = col0 + wn*BNh + nt*16 + l16;
      float bs = bias[col];
      #pragma unroll
      for (int reg = 0; reg < 4; ++reg){
        float y = acc[mt][nt][reg] + bs;
        if (act) y = LKY(y);
        long row = rowb + reg;
        if constexpr (OUTS){
          ushort_t h = f2bf(y);
          ushort_t l = f2bf(y - bf2f(h));
          long off = ((long)(col >> 3)*Mrows + row)*8 + (col & 7);
          Yh[off] = h; Yl[off] = l;
        } else {
          Y[row*(long)N + col] = y;
        }
      }
    }
  }
}

// ---------------------------------------------------------------------------
extern "C" void kernel_launch(void* const* d_in, const int* in_sizes, int n_in,
                              void* d_out, int out_size, void* d_ws, size_t ws_size,
                              hipStream_t stream) {
  const float* in0    = (const float*)d_in[0];
  const float* enc_w1 = (const float*)d_in[1];
  const float* enc_b1 = (const float*)d_in[2];
  const float* enc_w2 = (const float*)d_in[3];
  const float* enc_b2 = (const float*)d_in[4];
  const float* enc_w3 = (const float*)d_in[5];
  const float* enc_b3 = (const float*)d_in[6];
  const float* A_w    = (const float*)d_in[7];
  const float* B_w    = (const float*)d_in[8];
  const float* dec_w1 = (const float*)d_in[9];
  const float* dec_b1 = (const float*)d_in[10];
  const float* dec_w2 = (const float*)d_in[11];
  const float* dec_b2 = (const float*)d_in[12];
  const float* dec_w3 = (const float*)d_in[13];
  const float* dec_b3 = (const float*)d_in[14];
  float* out = (float*)d_out;

  // ---- workspace layout (float slots); total 9,437,184 fl = 37.75 MB ----
  float* ws    = (float*)d_ws;
  float* h1enc = ws;                      // 32768
  float* h2enc = ws + 32768;              // 32768
  float* s2    = ws + 65536;              // A^2
  float* s3    = ws + 131072;             // A^3
  float* s4    = ws + 196608;             // A^4
  float* s8    = ws + 262144;             // A^8
  float* s16   = ws + 327680;             // A^16
  float* s32   = ws + 393216;             // A^32
  float* s64   = ws + 458752;             // A^64
  ushort_t* Whp_d = (ushort_t*)(ws + 524288);   // decoder W planes
  ushort_t* Wlp_d = (ushort_t*)(ws + 786432);
  float* Rf    = ws + 1048576;            // R-pool: 8,388,608 fl
  // scan-phase layout of R:
  ushort_t* AjH = (ushort_t*)Rf;                // 8 planes x 65536 ush
  ushort_t* AjL = (ushort_t*)(Rf + 262144);
  ushort_t* BtH = (ushort_t*)(Rf + 524288);     // 8192 ush
  ushort_t* BtL = BtH + 8192;
  float* wend  = Rf + 532480;             // 2,097,152 (also KS-local ping buf)
  float* inits = Rf + 2629632;            // 2,097,152 (inits[0] = z0)
  float* g0    = Rf + 4726784;            // 262,144 (KS-global buf A)
  ushort_t* A64H = (ushort_t*)(Rf + 4988928);   // 65536 ush
  ushort_t* A64L = (ushort_t*)(Rf + 5021696);   // 65536 ush
  float* pb0   = Rf + 5054464;            // 2,097,152 (KS-local pong buf / LS)
  ushort_t* A8PH = (ushort_t*)(Rf + 7151616);   // 7 planes (A8^1..A8^7)
  ushort_t* A8PL = (ushort_t*)(Rf + 7380992);
  ushort_t* A64PH = (ushort_t*)(Rf + 7610368);  // 3 planes (A128,A256,A512)
  ushort_t* A64PL = (ushort_t*)(Rf + 7708672);
  float* f24   = Rf + 7806976;            // fp32 A^24
  float* f128  = Rf + 7872512;            // fp32 A^128
  float* f256  = Rf + 7938048;            // fp32 A^256
  float* g1    = Rf + 8003584;            // 262,144 (KS-global buf B)
  // decoder-phase aliases of R (scan data dead by then):
  ushort_t* h1h = (ushort_t*)Rf;
  ushort_t* h1l = (ushort_t*)(Rf + 2097152);
  ushort_t* h2h = (ushort_t*)(Rf + 4194304);
  ushort_t* h2l = (ushort_t*)(Rf + 6291456);
  // A^8 hi/lo planes in fragment order: AjH/AjL plane 7.
  ushort_t* A8H = AjH + 7*65536;
  ushort_t* A8L = AjL + 7*65536;

  // Encoder (only t=0 feeds the scan) -> z0 into inits[0]
  enc_dense<<<dim3(64,16), 256, 0, stream>>>(in0, Tt*Dd, enc_w1, enc_b1, h1enc, 256, 512, 1);
  enc_dense<<<dim3(64,16), 256, 0, stream>>>(h1enc, 512, enc_w2, enc_b2, h2enc, 512, 512, 1);
  enc_dense<<<dim3(64, 8), 256, 0, stream>>>(h2enc, 512, enc_w3, enc_b3, inits, 512, 256, 1);

  // A^j planes (j=1..8) + A8-power planes + A64-power planes for KS pass2
  prep_w<<<256, 256, 0, stream>>>(A_w, AjH, AjL, 256);                       // A^1 plane
  prep_bw<<<32, 256, 0, stream>>>(B_w, BtH, BtL);
  matmul_g<<<256, 256, 0, stream>>>(A_w, A_w, s2, AjH+1*65536, AjL+1*65536); // A^2
  matmul_g<<<256, 256, 0, stream>>>(s2, A_w, s3, AjH+2*65536, AjL+2*65536);  // A^3
  matmul_g<<<256, 256, 0, stream>>>(s2, s2, s4, AjH+3*65536, AjL+3*65536);   // A^4
  matmul_g<<<256, 256, 0, stream>>>(s4, A_w, nullptr, AjH+4*65536, AjL+4*65536); // A^5
  matmul_g<<<256, 256, 0, stream>>>(s4, s2, nullptr, AjH+5*65536, AjL+5*65536);  // A^6
  matmul_g<<<256, 256, 0, stream>>>(s4, s3, nullptr, AjH+6*65536, AjL+6*65536);  // A^7
  matmul_g<<<256, 256, 0, stream>>>(s4, s4, s8, A8H, A8L);                   // A^8 (+planes)
  prep_w<<<256, 256, 0, stream>>>(s8, A8PH, A8PL, 256);                      // A8^1 plane (slot 0)
  matmul_g<<<256, 256, 0, stream>>>(s8, s8, s16, A8PH+1*65536, A8PL+1*65536);   // A^16
  matmul_g<<<256, 256, 0, stream>>>(s16, s8, f24, A8PH+2*65536, A8PL+2*65536);  // A^24
  matmul_g<<<256, 256, 0, stream>>>(s16, s16, s32, A8PH+3*65536, A8PL+3*65536); // A^32
  matmul_g<<<256, 256, 0, stream>>>(s32, s8, nullptr, A8PH+4*65536, A8PL+4*65536);  // A^40
  matmul_g<<<256, 256, 0, stream>>>(s32, s16, nullptr, A8PH+5*65536, A8PL+5*65536); // A^48
  matmul_g<<<256, 256, 0, stream>>>(s32, f24, nullptr, A8PH+6*65536, A8PL+6*65536); // A^56
  matmul_g<<<256, 256, 0, stream>>>(s32, s32, s64, A64H, A64L);              // A^64 (+planes)
  matmul_g<<<256, 256, 0, stream>>>(s64, s64, f128, A64PH+0*65536, A64PL+0*65536);  // A^128
  matmul_g<<<256, 256, 0, stream>>>(f128, f128, f256, A64PH+1*65536, A64PL+1*65536);// A^256
  matmul_g<<<256, 256, 0, stream>>>(f256, f256, nullptr, A64PH+2*65536, A64PL+2*65536); // A^512

  // Decoder weight planes
  prep_w<<<512,  256, 0, stream>>>(dec_w1, Whp_d,          Wlp_d,          512);
  prep_w<<<1024, 256, 0, stream>>>(dec_w2, Whp_d + 131072, Wlp_d + 131072, 512);
  prep_w<<<512,  256, 0, stream>>>(dec_w3, Whp_d + 393216, Wlp_d + 393216, 256);

  // Pass 1: MFMA zero-init chunk scans; w[t] -> d_out, ends -> wend
  scan_mfma<<<NCh, 256, 0, stream>>>(in0, AjH, AjL, BtH, BtL, wend, out);

  // Pass 2a: KS-local — within-superchunk inclusive prefixes LS[c] over A^8.
  //   r1: wend -> pb0 (d=1, A8); r2: pb0 -> wend (d=2, A16); r3: wend -> pb0 (d=4, A32)
  ks_round<<<128, 512, 0, stream>>>(A8H, A8L, wend, nullptr, nullptr, pb0, Bb*Ll, 1, 1, 0);
  ks_round<<<128, 512, 0, stream>>>(A8PH+1*65536, A8PL+1*65536, pb0, nullptr, nullptr, wend, Bb*Ll, 2, 1, 0);
  ks_round<<<128, 512, 0, stream>>>(A8PH+3*65536, A8PL+3*65536, wend, nullptr, nullptr, pb0, Bb*Ll, 4, 1, 0);
  // Pass 2b: KS-global — superchunk inits h[s] over A^64 (init: z0, LS ends).
  ks_round<<<16, 512, 0, stream>>>(A64H, A64L, nullptr, inits, pb0, g1, Bb*Ll, 1, 0, 1);
  ks_round<<<16, 512, 0, stream>>>(A64PH+0*65536, A64PL+0*65536, g1, nullptr, nullptr, g0, Bb*Ll, 2, 0, 0);
  ks_round<<<16, 512, 0, stream>>>(A64PH+1*65536, A64PL+1*65536, g0, nullptr, nullptr, g1, Bb*Ll, 4, 0, 0);
  ks_round<<<16, 512, 0, stream>>>(A64PH+2*65536, A64PL+2*65536, g1, nullptr, nullptr, inits, (long)SC*Bb*Ll, 8, 0, 0);
  // Pass 2c: parallel replay correction: inits[8s+i] = LS[8s+i-1] + h[s]@A8^i
  replay_corr<<<dim3(7, 16), 512, 0, stream>>>(A8PH, A8PL, pb0, inits);

  // Pass 3 (parallel corrections): out[b, c*8+j, :] += inits[c] @ A^(j+1)
  gemm_corr<<<dim3(2, 64, 8), 256, 0, stream>>>(inits, AjH, AjL, out);

  // Decoder: 3-layer MLP, split-bf16 MFMA, 64x128 tiles
  for (int rc = 0; rc < DEC_CHUNKS; ++rc){
    const float* zc = out + (long)rc*DEC_ROWS*Ll;
    float* oc       = out + (long)rc*DEC_ROWS*Ll;
    gemm_mfma<64,128,false,true><<<dim3(Ee/128, DEC_ROWS/64), 256, 0, stream>>>(
        zc, nullptr, nullptr, Whp_d, Wlp_d, dec_b1, nullptr, h1h, h1l, DEC_ROWS, Ll, Ee, 1);
    gemm_mfma<64,128,true,true><<<dim3(Ee/128, DEC_ROWS/64), 256, 0, stream>>>(
        nullptr, h1h, h1l, Whp_d + 131072, Wlp_d + 131072, dec_b2, nullptr, h2h, h2l, DEC_ROWS, Ee, Ee, 1);
    gemm_mfma<64,128,true,false><<<dim3(Ss/128, DEC_ROWS/64), 256, 0, stream>>>(
        nullptr, h2h, h2l, Whp_d + 393216, Wlp_d + 393216, dec_b3, oc, nullptr, nullptr, DEC_ROWS, Ee, Ss, 0);
  }
}